// Round 9
// baseline (411.956 us; speedup 1.0000x reference)
//
#include <hip/hip_runtime.h>
#include <hip/hip_bf16.h>

#define NUM_NODES 50000
#define NUM_EDGES 800000
#define NUM_HEADS 8
#define HEAD_DIM 32
#define SCAN_BLOCKS 49

typedef unsigned short ushort8 __attribute__((ext_vector_type(8)));
typedef float f32x4 __attribute__((ext_vector_type(4)));
typedef __bf16 bf16x8 __attribute__((ext_vector_type(8)));

union BF8 { ushort8 u; bf16x8 b; };

__device__ __forceinline__ unsigned float_to_key(float f) {
    int i = __float_as_int(f);
    return (i >= 0) ? ((unsigned)i | 0x80000000u) : ~(unsigned)i;
}
__device__ __forceinline__ float key_to_float(unsigned u) {
    unsigned b = (u & 0x80000000u) ? (u & 0x7fffffffu) : ~u;
    return __int_as_float((int)b);
}
__device__ __forceinline__ float bf2f(unsigned short u) {
    return __uint_as_float(((unsigned)u) << 16);
}
__device__ __forceinline__ unsigned short f2bf(float f) {
    unsigned u = __float_as_uint(f);
    unsigned r = (u + 0x7fffu + ((u >> 16) & 1u)) >> 16;
    return (unsigned short)r;
}

// ---------- CSR build ----------
__global__ __launch_bounds__(256) void deg_kernel(const int* __restrict__ dst_idx, int* __restrict__ deg) {
    int e = blockIdx.x * 256 + threadIdx.x;
    if (e < NUM_EDGES) atomicAdd(&deg[dst_idx[e]], 1);
}

__global__ __launch_bounds__(1024) void scanA_kernel(
    const int* __restrict__ deg, int* __restrict__ offs, int* __restrict__ blocksum)
{
    __shared__ int buf[1024];
    int tid = threadIdx.x;
    int i = blockIdx.x * 1024 + tid;
    int v = (i < NUM_NODES) ? deg[i] : 0;
    buf[tid] = v;
    __syncthreads();
    for (int off = 1; off < 1024; off <<= 1) {
        int t = (tid >= off) ? buf[tid - off] : 0;
        __syncthreads();
        buf[tid] += t;
        __syncthreads();
    }
    if (i < NUM_NODES) offs[i] = buf[tid] - v;
    if (tid == 1023) blocksum[blockIdx.x] = buf[1023];
}

__global__ __launch_bounds__(64) void scanB_kernel(
    const int* __restrict__ blocksum, int* __restrict__ carry, int* __restrict__ offs)
{
    if (threadIdx.x == 0) {
        int acc = 0;
        for (int b = 0; b < SCAN_BLOCKS; b++) { carry[b] = acc; acc += blocksum[b]; }
        offs[NUM_NODES] = acc;
    }
}

__global__ __launch_bounds__(256) void scanC_kernel(
    int* __restrict__ offs, const int* __restrict__ carry, int* __restrict__ cursor)
{
    int i = blockIdx.x * 256 + threadIdx.x;
    if (i < NUM_NODES) {
        int v = offs[i] + carry[i >> 10];
        offs[i] = v;
        cursor[i] = v;
    }
}

__global__ __launch_bounds__(256) void fill2_kernel(
    const int* __restrict__ src_idx, const int* __restrict__ dst_idx,
    const float* __restrict__ edge_time, int* __restrict__ cursor,
    int* __restrict__ src_s, int* __restrict__ dst_s, float* __restrict__ et_s)
{
    int e = blockIdx.x * 256 + threadIdx.x;
    if (e < NUM_EDGES) {
        int d = dst_idx[e];
        int pos = atomicAdd(&cursor[d], 1);
        src_s[pos] = src_idx[e];
        dst_s[pos] = d;
        et_s[pos] = edge_time[e];
    }
}

// ---------- weight transpose+cvt: Wt[1024 n][256 k] bf16 ----------
__global__ __launch_bounds__(256) void wtrans_kernel(
    const float* __restrict__ Wq, const float* __restrict__ Wk,
    const float* __restrict__ Wv, const float* __restrict__ Wo,
    unsigned short* __restrict__ Wt)
{
    __shared__ float t[64][65];
    int nb = blockIdx.x * 64;
    int kb = blockIdx.y * 64;
    int g = nb >> 8;
    const float* W = (g == 0) ? Wq : (g == 1) ? Wk : (g == 2) ? Wv : Wo;
    int n0 = nb & 255;
    int tx = threadIdx.x & 63;
    int ty = threadIdx.x >> 6;
#pragma unroll
    for (int i = 0; i < 16; i++) {
        int k = i * 4 + ty;
        t[tx][k] = W[(size_t)(kb + k) * 256 + n0 + tx];
    }
    __syncthreads();
#pragma unroll
    for (int i = 0; i < 16; i++) {
        int n = i * 4 + ty;
        Wt[(size_t)(nb + n) * 256 + kb + tx] = f2bf(t[n][tx]);
    }
}

// ---------- QKV GEMM via MFMA, 32-row tiles; outputs HEAD-MAJOR [8][N][32] bf16 ----------
__global__ __launch_bounds__(256) void gemm_qkv_mfma5(
    const float* __restrict__ A, int M,
    const unsigned short* __restrict__ Wt,
    const float* __restrict__ b0, const float* __restrict__ b1, const float* __restrict__ b2,
    unsigned short* __restrict__ O0, unsigned short* __restrict__ O1, unsigned short* __restrict__ O2)
{
    __shared__ unsigned short As[32 * 256];   // 16 KB, 16B-chunk swizzle: c ^= (row&7)
    int tid = threadIdx.x;
    int rowbase = blockIdx.x * 32;

    // stage A -> bf16 LDS (OOB rows stage zeros)
    {
        int rsub = tid >> 6;          // 0..3
        int c4 = (tid & 63) * 4;
        int cchunk = (tid & 63) >> 1;
        int sub = (tid & 1);
#pragma unroll
        for (int it = 0; it < 8; it++) {
            int row = it * 4 + rsub;
            int grow = rowbase + row;
            float4 av = make_float4(0.f, 0.f, 0.f, 0.f);
            if (grow < M) av = *(const float4*)(A + (size_t)grow * 256 + c4);
            ushort4 o;
            o.x = f2bf(av.x); o.y = f2bf(av.y); o.z = f2bf(av.z); o.w = f2bf(av.w);
            unsigned byte = row * 512 + ((unsigned)(cchunk ^ (row & 7)) << 4) + sub * 8;
            *(ushort4*)((char*)As + byte) = o;
        }
    }
    __syncthreads();

    int lane = tid & 63;
    int wid = tid >> 6;      // wave owns cols [wid*64, wid*64+64)
    int l16 = lane & 15;
    int kg = lane >> 4;

#pragma unroll
    for (int p = 0; p < 3; p++) {      // q, k, v
        const float* bias = (p == 0) ? b0 : (p == 1) ? b1 : b2;
        unsigned short* O = (p == 0) ? O0 : (p == 1) ? O1 : O2;

        f32x4 acc[2][4];
#pragma unroll
        for (int m = 0; m < 2; m++)
#pragma unroll
            for (int n = 0; n < 4; n++) acc[m][n] = (f32x4)(0.0f);

        const unsigned short* wp[4];
#pragma unroll
        for (int n = 0; n < 4; n++)
            wp[n] = Wt + (size_t)(p * 256 + wid * 64 + n * 16 + l16) * 256 + kg * 8;

#pragma unroll
        for (int c2 = 0; c2 < 8; c2++) {
            bf16x8 wfr[4];
#pragma unroll
            for (int n = 0; n < 4; n++) {
                BF8 t; t.u = *(const ushort8*)(wp[n] + c2 * 32);
                wfr[n] = t.b;
            }
            bf16x8 afr[2];
#pragma unroll
            for (int m = 0; m < 2; m++) {
                int row = m * 16 + l16;
                int cchunk = (c2 * 4 + kg) ^ (row & 7);
                BF8 t;
                t.u = *(const ushort8*)((const char*)As + row * 512 + (cchunk << 4));
                afr[m] = t.b;
            }
#pragma unroll
            for (int m = 0; m < 2; m++)
#pragma unroll
                for (int n = 0; n < 4; n++)
                    acc[m][n] = __builtin_amdgcn_mfma_f32_16x16x32_bf16(wfr[n], afr[m], acc[m][n], 0, 0, 0);
        }

#pragma unroll
        for (int m = 0; m < 2; m++) {
            int node = rowbase + m * 16 + l16;
            if (node >= M) continue;
#pragma unroll
            for (int n = 0; n < 4; n++) {
                int lc = wid * 64 + n * 16 + kg * 4;
                float4 bv = *(const float4*)(bias + lc);
                ushort4 o;
                o.x = f2bf(acc[m][n][0] + bv.x);
                o.y = f2bf(acc[m][n][1] + bv.y);
                o.z = f2bf(acc[m][n][2] + bv.z);
                o.w = f2bf(acc[m][n][3] + bv.w);
                int hh = lc >> 5, dd = lc & 31;
                *(ushort4*)(O + ((size_t)hh * NUM_NODES + node) * 32 + dd) = o;
            }
        }
    }
}

// ---------- scores, head-pinned (h = blockIdx & 7 -> XCD), head-major output ----------
__global__ __launch_bounds__(256) void score3_kernel(
    const unsigned short* __restrict__ qh, const unsigned short* __restrict__ kh,
    const int* __restrict__ src_s, const int* __restrict__ dst_s,
    const float* __restrict__ et_s, const float* __restrict__ node_time,
    const float* __restrict__ Wt, const float* __restrict__ bt,
    float* __restrict__ scores, unsigned* __restrict__ partialmax)
{
    __shared__ unsigned sm;
    int tid = threadIdx.x;
    if (tid == 0) sm = 0u;
    __syncthreads();
    int h = blockIdx.x & 7;
    int blk = blockIdx.x >> 3;               // 0..127
    float wt0 = Wt[h], wt1 = Wt[8 + h], btv = bt[h];
    const unsigned short* qhh = qh + (size_t)h * NUM_NODES * 32;
    const unsigned short* khh = kh + (size_t)h * NUM_NODES * 32;
    float* sc_h = scores + (size_t)h * NUM_EDGES;
    unsigned mykey = 0u;
    for (int pos = blk * 256 + tid; pos < NUM_EDGES; pos += 128 * 256) {
        int s = src_s[pos], d = dst_s[pos];
        const ushort8* qp = (const ushort8*)(qhh + (size_t)d * 32);
        const ushort8* kp = (const ushort8*)(khh + (size_t)s * 32);
        float dotv = 0.f;
#pragma unroll
        for (int i = 0; i < 4; i++) {
            ushort8 a = qp[i], b = kp[i];
#pragma unroll
            for (int j = 0; j < 8; j++) dotv += bf2f(a[j]) * bf2f(b[j]);
        }
        float td = et_s[pos] - node_time[d];
        float tf0 = (td > 0.f) ? 1.f : ((td < 0.f) ? -1.f : 0.f);
        float tf1 = log1pf(fabsf(td) * (1.f / 3600.f));
        float sc = dotv * 0.17677669529663687f + (tf0 * wt0 + tf1 * wt1 + btv);
        sc_h[pos] = sc;
        unsigned kkey = float_to_key(sc);
        mykey = (kkey > mykey) ? kkey : mykey;
    }
#pragma unroll
    for (int off = 32; off > 0; off >>= 1) {
        unsigned o = __shfl_xor(mykey, off, 64);
        mykey = (o > mykey) ? o : mykey;
    }
    if ((tid & 63) == 0) atomicMax(&sm, mykey);
    __syncthreads();
    if (tid == 0) partialmax[blockIdx.x] = sm;
}

// partialmax[1024], entry i belongs to head i&7
__global__ __launch_bounds__(256) void reduce_max2_kernel(
    const unsigned* __restrict__ partialmax, float* __restrict__ headmax)
{
    int tid = threadIdx.x;
    int h = tid >> 5, lane = tid & 31;
    unsigned m = 0u;
#pragma unroll
    for (int k = 0; k < 4; k++) {
        unsigned v = partialmax[(lane + 32 * k) * 8 + h];
        m = (v > m) ? v : m;
    }
    for (int off = 16; off > 0; off >>= 1) {
        unsigned o = __shfl_down(m, off, 32);
        m = (o > m) ? o : m;
    }
    if (lane == 0) headmax[h] = key_to_float(m);
}

// ---------- p = exp(s - m) -> bf16, + global per-head sum partials ----------
__global__ __launch_bounds__(256) void pexp_kernel(
    const float* __restrict__ scores, const float* __restrict__ headmax,
    unsigned short* __restrict__ pb, float* __restrict__ partialsum)
{
    __shared__ float ssum;
    int tid = threadIdx.x;
    if (tid == 0) ssum = 0.f;
    __syncthreads();
    int h = blockIdx.x & 7;
    int blk = blockIdx.x >> 3;
    float m = headmax[h];
    const float* sc_h = scores + (size_t)h * NUM_EDGES;
    unsigned short* p_h = pb + (size_t)h * NUM_EDGES;
    float s = 0.f;
    for (int pos = blk * 256 + tid; pos < NUM_EDGES; pos += 128 * 256) {
        float p = __expf(sc_h[pos] - m);
        p_h[pos] = f2bf(p);
        s += p;
    }
#pragma unroll
    for (int off = 32; off > 0; off >>= 1) s += __shfl_xor(s, off, 64);
    if ((tid & 63) == 0) atomicAdd(&ssum, s);
    __syncthreads();
    if (tid == 0) partialsum[blockIdx.x] = ssum;
}

// partialsum[1024], entry i belongs to head i&7
__global__ __launch_bounds__(256) void reduce_psum_kernel(
    const float* __restrict__ partialsum, float* __restrict__ headinv)
{
    int tid = threadIdx.x;
    int h = tid >> 5, lane = tid & 31;
    float s = 0.f;
#pragma unroll
    for (int k = 0; k < 4; k++) s += partialsum[(lane + 32 * k) * 8 + h];
    for (int off = 16; off > 0; off >>= 1) s += __shfl_down(s, off, 32);
    if (lane == 0) headinv[h] = 1.f / s;
}

// ---------- aggregate: head-pinned; 8-lane group per node, lane = 4 dims ----------
__global__ __launch_bounds__(256) void aggregate6_kernel(
    const unsigned short* __restrict__ vh, const unsigned short* __restrict__ pb,
    const int* __restrict__ src_s, const int* __restrict__ offs,
    unsigned short* __restrict__ aggb)
{
    int tid = threadIdx.x;
    int h = blockIdx.x & 7;
    int chunk = blockIdx.x >> 3;
    int g = tid >> 3;            // 0..31 node within chunk
    int ln = tid & 7;            // 4-dim slot
    int node = chunk * 32 + g;
    const unsigned short* p_h = pb + (size_t)h * NUM_EDGES;
    const unsigned short* vhh = vh + (size_t)h * NUM_NODES * 32;
    int start = 0, end = 0;
    if (node < NUM_NODES) { start = offs[node]; end = offs[node + 1]; }
    f32x4 a0 = (f32x4)(0.f), a1 = (f32x4)(0.f);
    int cb = start;
    for (; cb + 2 <= end; cb += 2) {
        int s0 = src_s[cb], s1 = src_s[cb + 1];
        float p0 = bf2f(p_h[cb]), p1 = bf2f(p_h[cb + 1]);
        ushort4 v0 = *(const ushort4*)(vhh + (size_t)s0 * 32 + ln * 4);
        ushort4 v1 = *(const ushort4*)(vhh + (size_t)s1 * 32 + ln * 4);
        a0[0] += p0 * bf2f(v0.x); a0[1] += p0 * bf2f(v0.y);
        a0[2] += p0 * bf2f(v0.z); a0[3] += p0 * bf2f(v0.w);
        a1[0] += p1 * bf2f(v1.x); a1[1] += p1 * bf2f(v1.y);
        a1[2] += p1 * bf2f(v1.z); a1[3] += p1 * bf2f(v1.w);
    }
    if (cb < end) {
        int s0 = src_s[cb];
        float p0 = bf2f(p_h[cb]);
        ushort4 v0 = *(const ushort4*)(vhh + (size_t)s0 * 32 + ln * 4);
        a0[0] += p0 * bf2f(v0.x); a0[1] += p0 * bf2f(v0.y);
        a0[2] += p0 * bf2f(v0.z); a0[3] += p0 * bf2f(v0.w);
    }
    if (node < NUM_NODES) {
        ushort4 o;
        o.x = f2bf(a0[0] + a1[0]); o.y = f2bf(a0[1] + a1[1]);
        o.z = f2bf(a0[2] + a1[2]); o.w = f2bf(a0[3] + a1[3]);
        *(ushort4*)(aggb + ((size_t)h * NUM_NODES + node) * 32 + ln * 4) = o;
    }
}

// ---------- output GEMM, 32-row tiles: A = bf16 head-major agg scaled; out fp32 ----------
__global__ __launch_bounds__(256) void gemm_out_mfma5(
    const unsigned short* __restrict__ aggb, int M,
    const unsigned short* __restrict__ Wt,
    const float* __restrict__ bias, const float* __restrict__ kscale,
    float* __restrict__ C)
{
    __shared__ unsigned short As[32 * 256];
    int tid = threadIdx.x;
    int rowbase = blockIdx.x * 32;

    {
        int rsub = tid >> 6;
        int c4 = (tid & 63) * 4;
        int cchunk = (tid & 63) >> 1;
        int sub = (tid & 1);
        int hh = c4 >> 5, dd = c4 & 31;
        float ks = kscale[hh];
#pragma unroll
        for (int it = 0; it < 8; it++) {
            int row = it * 4 + rsub;
            int grow = rowbase + row;
            ushort4 av = make_ushort4(0, 0, 0, 0);
            if (grow < M) av = *(const ushort4*)(aggb + ((size_t)hh * NUM_NODES + grow) * 32 + dd);
            ushort4 o;
            o.x = f2bf(bf2f(av.x) * ks); o.y = f2bf(bf2f(av.y) * ks);
            o.z = f2bf(bf2f(av.z) * ks); o.w = f2bf(bf2f(av.w) * ks);
            unsigned byte = row * 512 + ((unsigned)(cchunk ^ (row & 7)) << 4) + sub * 8;
            *(ushort4*)((char*)As + byte) = o;
        }
    }
    __syncthreads();

    int lane = tid & 63;
    int wid = tid >> 6;
    int l16 = lane & 15;
    int kg = lane >> 4;

    f32x4 acc[2][4];
#pragma unroll
    for (int m = 0; m < 2; m++)
#pragma unroll
        for (int n = 0; n < 4; n++) acc[m][n] = (f32x4)(0.0f);

    const unsigned short* wp[4];
#pragma unroll
    for (int n = 0; n < 4; n++)
        wp[n] = Wt + (size_t)(wid * 64 + n * 16 + l16) * 256 + kg * 8;

#pragma unroll
    for (int c2 = 0; c2 < 8; c2++) {
        bf16x8 wfr[4];
#pragma unroll
        for (int n = 0; n < 4; n++) {
            BF8 t; t.u = *(const ushort8*)(wp[n] + c2 * 32);
            wfr[n] = t.b;
        }
        bf16x8 afr[2];
#pragma unroll
        for (int m = 0; m < 2; m++) {
            int row = m * 16 + l16;
            int cchunk = (c2 * 4 + kg) ^ (row & 7);
            BF8 t;
            t.u = *(const ushort8*)((const char*)As + row * 512 + (cchunk << 4));
            afr[m] = t.b;
        }
#pragma unroll
        for (int m = 0; m < 2; m++)
#pragma unroll
            for (int n = 0; n < 4; n++)
                acc[m][n] = __builtin_amdgcn_mfma_f32_16x16x32_bf16(wfr[n], afr[m], acc[m][n], 0, 0, 0);
    }

#pragma unroll
    for (int m = 0; m < 2; m++) {
        int node = rowbase + m * 16 + l16;
        if (node >= M) continue;
#pragma unroll
        for (int n = 0; n < 4; n++) {
            int col = wid * 64 + n * 16 + kg * 4;
            float4 bv = *(const float4*)(bias + col);
            float4 o;
            o.x = acc[m][n][0] + bv.x;
            o.y = acc[m][n][1] + bv.y;
            o.z = acc[m][n][2] + bv.z;
            o.w = acc[m][n][3] + bv.w;
            *(float4*)(C + (size_t)node * 256 + col) = o;
        }
    }
}

extern "C" void kernel_launch(void* const* d_in, const int* in_sizes, int n_in,
                              void* d_out, int out_size, void* d_ws, size_t ws_size,
                              hipStream_t stream) {
    const float* x = (const float*)d_in[0];
    const int* ei = (const int*)d_in[1];
    const int* src_idx = ei;
    const int* dst_idx = ei + NUM_EDGES;
    const float* edge_time = (const float*)d_in[2];
    const float* node_time = (const float*)d_in[3];
    const float* Wq = (const float*)d_in[4];  const float* bq = (const float*)d_in[5];
    const float* Wk = (const float*)d_in[6];  const float* bk = (const float*)d_in[7];
    const float* Wv = (const float*)d_in[8];  const float* bv = (const float*)d_in[9];
    const float* Wt = (const float*)d_in[10]; const float* bt = (const float*)d_in[11];
    const float* Wo = (const float*)d_in[12]; const float* bo = (const float*)d_in[13];
    float* out = (float*)d_out;

    char* w = (char*)d_ws;
    unsigned short* qb = (unsigned short*)w; w += (size_t)NUM_NODES * 256 * 2;  // [8][N][32]
    unsigned short* kb = (unsigned short*)w; w += (size_t)NUM_NODES * 256 * 2;  // [8][N][32]
    unsigned short* vb = (unsigned short*)w; w += (size_t)NUM_NODES * 256 * 2;  // [8][N][32]
    float* scores = (float*)w;      w += (size_t)NUM_EDGES * 8 * 4;             // [8][E]
    unsigned short* pb = (unsigned short*)w; w += (size_t)NUM_EDGES * 8 * 2;    // [8][E] bf16
    unsigned short* aggb = (unsigned short*)w; w += (size_t)NUM_NODES * 256 * 2; // [8][N][32]
    int* src_s = (int*)w;           w += (size_t)NUM_EDGES * 4;
    int* dst_s = (int*)w;           w += (size_t)NUM_EDGES * 4;
    float* et_s = (float*)w;        w += (size_t)NUM_EDGES * 4;
    int* deg = (int*)w;             w += (size_t)NUM_NODES * 4;
    int* offs = (int*)w;            w += (size_t)(NUM_NODES + 1) * 4;
    int* cursor = (int*)w;          w += (size_t)NUM_NODES * 4;
    unsigned* partialmax = (unsigned*)w; w += 1024 * 4;
    float* partialsum = (float*)w;  w += 1024 * 4;
    float* headmax = (float*)w;     w += 8 * 4;
    float* headinv = (float*)w;     w += 8 * 4;
    int* blocksum = (int*)w;        w += 64 * 4;
    int* bcarry = (int*)w;          w += 64 * 4;
    unsigned short* Wtb = (unsigned short*)w; w += (size_t)1024 * 256 * 2;

    hipMemsetAsync(deg, 0, (size_t)NUM_NODES * 4, stream);

    // weight transpose + bf16 cvt (q,k,v,o)
    dim3 gw(16, 4);
    wtrans_kernel<<<gw, 256, 0, stream>>>(Wq, Wk, Wv, Wo, Wtb);

    // CSR by dst (parallel scan)
    deg_kernel<<<(NUM_EDGES + 255) / 256, 256, 0, stream>>>(dst_idx, deg);
    scanA_kernel<<<SCAN_BLOCKS, 1024, 0, stream>>>(deg, offs, blocksum);
    scanB_kernel<<<1, 64, 0, stream>>>(blocksum, bcarry, offs);
    scanC_kernel<<<(NUM_NODES + 255) / 256, 256, 0, stream>>>(offs, bcarry, cursor);
    fill2_kernel<<<(NUM_EDGES + 255) / 256, 256, 0, stream>>>(src_idx, dst_idx, edge_time,
                                                              cursor, src_s, dst_s, et_s);

    // QKV projection -> head-major bf16 q/k/v  (32-row tiles)
    gemm_qkv_mfma5<<<(NUM_NODES + 31) / 32, 256, 0, stream>>>(
        x, NUM_NODES, Wtb, bq, bk, bv, qb, kb, vb);

    // scores (head-pinned to XCDs) + per-head max
    score3_kernel<<<1024, 256, 0, stream>>>(qb, kb, src_s, dst_s, et_s, node_time,
                                            Wt, bt, scores, partialmax);
    reduce_max2_kernel<<<1, 256, 0, stream>>>(partialmax, headmax);

    // p = exp(s-m) bf16 + global per-head sums
    pexp_kernel<<<1024, 256, 0, stream>>>(scores, headmax, pb, partialsum);
    reduce_psum_kernel<<<1, 256, 0, stream>>>(partialsum, headinv);

    // aggregate (head-pinned, 8-lane groups, vectorized v rows)
    aggregate6_kernel<<<((NUM_NODES + 31) / 32) * 8, 256, 0, stream>>>(
        vb, pb, src_s, offs, aggb);

    // output projection with per-head 1/sum folded into staging (32-row tiles)
    gemm_out_mfma5<<<(NUM_NODES + 31) / 32, 256, 0, stream>>>(
        aggb, NUM_NODES, Wtb + (size_t)768 * 256, bo, headinv, out);
}

// Round 10
// 371.264 us; speedup vs baseline: 1.1096x; 1.1096x over previous
//
#include <hip/hip_runtime.h>
#include <hip/hip_bf16.h>

#define NUM_NODES 50000
#define NUM_EDGES 800000
#define NUM_HEADS 8
#define HEAD_DIM 32
#define SCAN_BLOCKS 49
#define NCHUNK 782   // ceil(50000/64)

typedef unsigned short ushort8 __attribute__((ext_vector_type(8)));
typedef float f32x4 __attribute__((ext_vector_type(4)));
typedef __bf16 bf16x8 __attribute__((ext_vector_type(8)));

union BF8 { ushort8 u; bf16x8 b; };

__device__ __forceinline__ unsigned float_to_key(float f) {
    int i = __float_as_int(f);
    return (i >= 0) ? ((unsigned)i | 0x80000000u) : ~(unsigned)i;
}
__device__ __forceinline__ float key_to_float(unsigned u) {
    unsigned b = (u & 0x80000000u) ? (u & 0x7fffffffu) : ~u;
    return __int_as_float((int)b);
}
__device__ __forceinline__ float bf2f(unsigned short u) {
    return __uint_as_float(((unsigned)u) << 16);
}
__device__ __forceinline__ unsigned short f2bf(float f) {
    unsigned u = __float_as_uint(f);
    unsigned r = (u + 0x7fffu + ((u >> 16) & 1u)) >> 16;
    return (unsigned short)r;
}

// ---------- CSR build ----------
__global__ __launch_bounds__(256) void deg_kernel(const int* __restrict__ dst_idx, int* __restrict__ deg) {
    int e = blockIdx.x * 256 + threadIdx.x;
    if (e < NUM_EDGES) atomicAdd(&deg[dst_idx[e]], 1);
}

__global__ __launch_bounds__(1024) void scanA_kernel(
    const int* __restrict__ deg, int* __restrict__ offs, int* __restrict__ blocksum)
{
    __shared__ int buf[1024];
    int tid = threadIdx.x;
    int i = blockIdx.x * 1024 + tid;
    int v = (i < NUM_NODES) ? deg[i] : 0;
    buf[tid] = v;
    __syncthreads();
    for (int off = 1; off < 1024; off <<= 1) {
        int t = (tid >= off) ? buf[tid - off] : 0;
        __syncthreads();
        buf[tid] += t;
        __syncthreads();
    }
    if (i < NUM_NODES) offs[i] = buf[tid] - v;
    if (tid == 1023) blocksum[blockIdx.x] = buf[1023];
}

__global__ __launch_bounds__(64) void scanB_kernel(
    const int* __restrict__ blocksum, int* __restrict__ carry, int* __restrict__ offs)
{
    if (threadIdx.x == 0) {
        int acc = 0;
        for (int b = 0; b < SCAN_BLOCKS; b++) { carry[b] = acc; acc += blocksum[b]; }
        offs[NUM_NODES] = acc;
    }
}

__global__ __launch_bounds__(256) void scanC_kernel(
    int* __restrict__ offs, const int* __restrict__ carry, int* __restrict__ cursor)
{
    int i = blockIdx.x * 256 + threadIdx.x;
    if (i < NUM_NODES) {
        int v = offs[i] + carry[i >> 10];
        offs[i] = v;
        cursor[i] = v;
    }
}

__global__ __launch_bounds__(256) void fill2_kernel(
    const int* __restrict__ src_idx, const int* __restrict__ dst_idx,
    const float* __restrict__ edge_time, int* __restrict__ cursor,
    int* __restrict__ src_s, int* __restrict__ dst_s, float* __restrict__ et_s)
{
    int e = blockIdx.x * 256 + threadIdx.x;
    if (e < NUM_EDGES) {
        int d = dst_idx[e];
        int pos = atomicAdd(&cursor[d], 1);
        src_s[pos] = src_idx[e];
        dst_s[pos] = d;
        et_s[pos] = edge_time[e];
    }
}

// ---------- weight transpose+cvt: Wt[1024 n][256 k] bf16 ----------
__global__ __launch_bounds__(256) void wtrans_kernel(
    const float* __restrict__ Wq, const float* __restrict__ Wk,
    const float* __restrict__ Wv, const float* __restrict__ Wo,
    unsigned short* __restrict__ Wt)
{
    __shared__ float t[64][65];
    int nb = blockIdx.x * 64;
    int kb = blockIdx.y * 64;
    int g = nb >> 8;
    const float* W = (g == 0) ? Wq : (g == 1) ? Wk : (g == 2) ? Wv : Wo;
    int n0 = nb & 255;
    int tx = threadIdx.x & 63;
    int ty = threadIdx.x >> 6;
#pragma unroll
    for (int i = 0; i < 16; i++) {
        int k = i * 4 + ty;
        t[tx][k] = W[(size_t)(kb + k) * 256 + n0 + tx];
    }
    __syncthreads();
#pragma unroll
    for (int i = 0; i < 16; i++) {
        int n = i * 4 + ty;
        Wt[(size_t)(nb + n) * 256 + kb + tx] = f2bf(t[n][tx]);
    }
}

// ---------- QKV GEMM: W in registers, 8 waves x 32 cols, grid-stride row chunks ----------
__global__ __launch_bounds__(512) void gemm_qkv_reg(
    const float* __restrict__ A, int M,
    const unsigned short* __restrict__ Wt,
    const float* __restrict__ b0, const float* __restrict__ b1, const float* __restrict__ b2,
    unsigned short* __restrict__ O0, unsigned short* __restrict__ O1, unsigned short* __restrict__ O2)
{
    __shared__ unsigned short As[64 * 256];   // 32 KB, swizzle c ^= (row&7)
    int tid = threadIdx.x;
    int p = blockIdx.y;
    const float* bias = (p == 0) ? b0 : (p == 1) ? b1 : b2;
    unsigned short* O = (p == 0) ? O0 : (p == 1) ? O1 : O2;

    int lane = tid & 63;
    int wid = tid >> 6;      // 0..7, wave owns cols [wid*32, wid*32+32)
    int l16 = lane & 15;
    int kg = lane >> 4;

    // W fragments for full K=256, loaded once
    bf16x8 wfr[2][8];
#pragma unroll
    for (int n = 0; n < 2; n++) {
        const unsigned short* wp = Wt + (size_t)(p * 256 + wid * 32 + n * 16 + l16) * 256 + kg * 8;
#pragma unroll
        for (int c2 = 0; c2 < 8; c2++) {
            BF8 t; t.u = *(const ushort8*)(wp + c2 * 32);
            wfr[n][c2] = t.b;
        }
    }

    int rsub = tid >> 6;          // 0..7
    int c4 = (tid & 63) * 4;
    int cchunk = (tid & 63) >> 1;
    int sub = (tid & 1);

    for (int chunk = blockIdx.x; chunk < NCHUNK; chunk += gridDim.x) {
        int rowbase = chunk * 64;
        // stage A -> bf16 LDS
#pragma unroll
        for (int it = 0; it < 8; it++) {
            int row = it * 8 + rsub;
            int grow = rowbase + row;
            float4 av = make_float4(0.f, 0.f, 0.f, 0.f);
            if (grow < M) av = *(const float4*)(A + (size_t)grow * 256 + c4);
            ushort4 o;
            o.x = f2bf(av.x); o.y = f2bf(av.y); o.z = f2bf(av.z); o.w = f2bf(av.w);
            unsigned byte = row * 512 + ((unsigned)(cchunk ^ (row & 7)) << 4) + sub * 8;
            *(ushort4*)((char*)As + byte) = o;
        }
        __syncthreads();

        f32x4 acc[4][2];
#pragma unroll
        for (int m = 0; m < 4; m++)
#pragma unroll
            for (int n = 0; n < 2; n++) acc[m][n] = (f32x4)(0.0f);

#pragma unroll
        for (int c2 = 0; c2 < 8; c2++) {
            bf16x8 afr[4];
#pragma unroll
            for (int m = 0; m < 4; m++) {
                int row = m * 16 + l16;
                int cc = (c2 * 4 + kg) ^ (row & 7);
                BF8 t;
                t.u = *(const ushort8*)((const char*)As + row * 512 + (cc << 4));
                afr[m] = t.b;
            }
#pragma unroll
            for (int m = 0; m < 4; m++)
#pragma unroll
                for (int n = 0; n < 2; n++)
                    acc[m][n] = __builtin_amdgcn_mfma_f32_16x16x32_bf16(wfr[n][c2], afr[m], acc[m][n], 0, 0, 0);
        }

#pragma unroll
        for (int m = 0; m < 4; m++) {
            int node = rowbase + m * 16 + l16;
            if (node < M) {
#pragma unroll
                for (int n = 0; n < 2; n++) {
                    int lc = wid * 32 + n * 16 + kg * 4;
                    float4 bv = *(const float4*)(bias + lc);
                    ushort4 o;
                    o.x = f2bf(acc[m][n][0] + bv.x);
                    o.y = f2bf(acc[m][n][1] + bv.y);
                    o.z = f2bf(acc[m][n][2] + bv.z);
                    o.w = f2bf(acc[m][n][3] + bv.w);
                    int hh = lc >> 5, dd = lc & 31;
                    *(ushort4*)(O + ((size_t)hh * NUM_NODES + node) * 32 + dd) = o;
                }
            }
        }
        __syncthreads();
    }
}

// ---------- output GEMM: W in registers, A = bf16 head-major agg scaled per head ----------
__global__ __launch_bounds__(512) void gemm_out_reg(
    const unsigned short* __restrict__ aggb, int M,
    const unsigned short* __restrict__ Wt,
    const float* __restrict__ bias, const float* __restrict__ kscale,
    float* __restrict__ C)
{
    __shared__ unsigned short As[64 * 256];
    int tid = threadIdx.x;

    int lane = tid & 63;
    int wid = tid >> 6;
    int l16 = lane & 15;
    int kg = lane >> 4;

    bf16x8 wfr[2][8];
#pragma unroll
    for (int n = 0; n < 2; n++) {
        const unsigned short* wp = Wt + (size_t)(wid * 32 + n * 16 + l16) * 256 + kg * 8;
#pragma unroll
        for (int c2 = 0; c2 < 8; c2++) {
            BF8 t; t.u = *(const ushort8*)(wp + c2 * 32);
            wfr[n][c2] = t.b;
        }
    }

    int row8 = tid >> 6;       // 0..7
    int cq = tid & 63;         // col quad
    int c4 = cq * 4;
    int hh = c4 >> 5, dd = c4 & 31;
    float ks = kscale[hh];
    int cchunk = cq >> 1, sub = cq & 1;

    for (int chunk = blockIdx.x; chunk < NCHUNK; chunk += gridDim.x) {
        int rowbase = chunk * 64;
#pragma unroll
        for (int it = 0; it < 8; it++) {
            int row = it * 8 + row8;
            int grow = rowbase + row;
            ushort4 av = make_ushort4(0, 0, 0, 0);
            if (grow < M) av = *(const ushort4*)(aggb + ((size_t)hh * NUM_NODES + grow) * 32 + dd);
            ushort4 o;
            o.x = f2bf(bf2f(av.x) * ks); o.y = f2bf(bf2f(av.y) * ks);
            o.z = f2bf(bf2f(av.z) * ks); o.w = f2bf(bf2f(av.w) * ks);
            unsigned byte = row * 512 + ((unsigned)(cchunk ^ (row & 7)) << 4) + sub * 8;
            *(ushort4*)((char*)As + byte) = o;
        }
        __syncthreads();

        f32x4 acc[4][2];
#pragma unroll
        for (int m = 0; m < 4; m++)
#pragma unroll
            for (int n = 0; n < 2; n++) acc[m][n] = (f32x4)(0.0f);

#pragma unroll
        for (int c2 = 0; c2 < 8; c2++) {
            bf16x8 afr[4];
#pragma unroll
            for (int m = 0; m < 4; m++) {
                int row = m * 16 + l16;
                int cc = (c2 * 4 + kg) ^ (row & 7);
                BF8 t;
                t.u = *(const ushort8*)((const char*)As + row * 512 + (cc << 4));
                afr[m] = t.b;
            }
#pragma unroll
            for (int m = 0; m < 4; m++)
#pragma unroll
                for (int n = 0; n < 2; n++)
                    acc[m][n] = __builtin_amdgcn_mfma_f32_16x16x32_bf16(wfr[n][c2], afr[m], acc[m][n], 0, 0, 0);
        }

#pragma unroll
        for (int m = 0; m < 4; m++) {
            int node = rowbase + m * 16 + l16;
            if (node < M) {
#pragma unroll
                for (int n = 0; n < 2; n++) {
                    int col = wid * 32 + n * 16 + kg * 4;
                    float4 bv = *(const float4*)(bias + col);
                    float4 o;
                    o.x = acc[m][n][0] + bv.x;
                    o.y = acc[m][n][1] + bv.y;
                    o.z = acc[m][n][2] + bv.z;
                    o.w = acc[m][n][3] + bv.w;
                    *(float4*)(C + (size_t)node * 256 + col) = o;
                }
            }
        }
        __syncthreads();
    }
}

// ---------- scores, head-pinned (h = blockIdx & 7 -> XCD), head-major output ----------
__global__ __launch_bounds__(256) void score3_kernel(
    const unsigned short* __restrict__ qh, const unsigned short* __restrict__ kh,
    const int* __restrict__ src_s, const int* __restrict__ dst_s,
    const float* __restrict__ et_s, const float* __restrict__ node_time,
    const float* __restrict__ Wt, const float* __restrict__ bt,
    float* __restrict__ scores, unsigned* __restrict__ partialmax)
{
    __shared__ unsigned sm;
    int tid = threadIdx.x;
    if (tid == 0) sm = 0u;
    __syncthreads();
    int h = blockIdx.x & 7;
    int blk = blockIdx.x >> 3;               // 0..127
    float wt0 = Wt[h], wt1 = Wt[8 + h], btv = bt[h];
    const unsigned short* qhh = qh + (size_t)h * NUM_NODES * 32;
    const unsigned short* khh = kh + (size_t)h * NUM_NODES * 32;
    float* sc_h = scores + (size_t)h * NUM_EDGES;
    unsigned mykey = 0u;
    for (int pos = blk * 256 + tid; pos < NUM_EDGES; pos += 128 * 256) {
        int s = src_s[pos], d = dst_s[pos];
        const ushort8* qp = (const ushort8*)(qhh + (size_t)d * 32);
        const ushort8* kp = (const ushort8*)(khh + (size_t)s * 32);
        float dotv = 0.f;
#pragma unroll
        for (int i = 0; i < 4; i++) {
            ushort8 a = qp[i], b = kp[i];
#pragma unroll
            for (int j = 0; j < 8; j++) dotv += bf2f(a[j]) * bf2f(b[j]);
        }
        float td = et_s[pos] - node_time[d];
        float tf0 = (td > 0.f) ? 1.f : ((td < 0.f) ? -1.f : 0.f);
        float tf1 = log1pf(fabsf(td) * (1.f / 3600.f));
        float sc = dotv * 0.17677669529663687f + (tf0 * wt0 + tf1 * wt1 + btv);
        sc_h[pos] = sc;
        unsigned kkey = float_to_key(sc);
        mykey = (kkey > mykey) ? kkey : mykey;
    }
#pragma unroll
    for (int off = 32; off > 0; off >>= 1) {
        unsigned o = __shfl_xor(mykey, off, 64);
        mykey = (o > mykey) ? o : mykey;
    }
    if ((tid & 63) == 0) atomicMax(&sm, mykey);
    __syncthreads();
    if (tid == 0) partialmax[blockIdx.x] = sm;
}

// partialmax[1024], entry i belongs to head i&7
__global__ __launch_bounds__(256) void reduce_max2_kernel(
    const unsigned* __restrict__ partialmax, float* __restrict__ headmax)
{
    int tid = threadIdx.x;
    int h = tid >> 5, lane = tid & 31;
    unsigned m = 0u;
#pragma unroll
    for (int k = 0; k < 4; k++) {
        unsigned v = partialmax[(lane + 32 * k) * 8 + h];
        m = (v > m) ? v : m;
    }
    for (int off = 16; off > 0; off >>= 1) {
        unsigned o = __shfl_down(m, off, 32);
        m = (o > m) ? o : m;
    }
    if (lane == 0) headmax[h] = key_to_float(m);
}

// ---------- p = exp(s - m) -> bf16, + global per-head sum partials ----------
__global__ __launch_bounds__(256) void pexp_kernel(
    const float* __restrict__ scores, const float* __restrict__ headmax,
    unsigned short* __restrict__ pb, float* __restrict__ partialsum)
{
    __shared__ float ssum;
    int tid = threadIdx.x;
    if (tid == 0) ssum = 0.f;
    __syncthreads();
    int h = blockIdx.x & 7;
    int blk = blockIdx.x >> 3;
    float m = headmax[h];
    const float* sc_h = scores + (size_t)h * NUM_EDGES;
    unsigned short* p_h = pb + (size_t)h * NUM_EDGES;
    float s = 0.f;
    for (int pos = blk * 256 + tid; pos < NUM_EDGES; pos += 128 * 256) {
        float p = __expf(sc_h[pos] - m);
        p_h[pos] = f2bf(p);
        s += p;
    }
#pragma unroll
    for (int off = 32; off > 0; off >>= 1) s += __shfl_xor(s, off, 64);
    if ((tid & 63) == 0) atomicAdd(&ssum, s);
    __syncthreads();
    if (tid == 0) partialsum[blockIdx.x] = ssum;
}

// partialsum[1024], entry i belongs to head i&7
__global__ __launch_bounds__(256) void reduce_psum_kernel(
    const float* __restrict__ partialsum, float* __restrict__ headinv)
{
    int tid = threadIdx.x;
    int h = tid >> 5, lane = tid & 31;
    float s = 0.f;
#pragma unroll
    for (int k = 0; k < 4; k++) s += partialsum[(lane + 32 * k) * 8 + h];
    for (int off = 16; off > 0; off >>= 1) s += __shfl_down(s, off, 32);
    if (lane == 0) headinv[h] = 1.f / s;
}

// ---------- aggregate: head-pinned; 8-lane group per node, lane = 4 dims ----------
__global__ __launch_bounds__(256) void aggregate6_kernel(
    const unsigned short* __restrict__ vh, const unsigned short* __restrict__ pb,
    const int* __restrict__ src_s, const int* __restrict__ offs,
    unsigned short* __restrict__ aggb)
{
    int tid = threadIdx.x;
    int h = blockIdx.x & 7;
    int chunk = blockIdx.x >> 3;
    int g = tid >> 3;            // 0..31 node within chunk
    int ln = tid & 7;            // 4-dim slot
    int node = chunk * 32 + g;
    const unsigned short* p_h = pb + (size_t)h * NUM_EDGES;
    const unsigned short* vhh = vh + (size_t)h * NUM_NODES * 32;
    int start = 0, end = 0;
    if (node < NUM_NODES) { start = offs[node]; end = offs[node + 1]; }
    f32x4 a0 = (f32x4)(0.f), a1 = (f32x4)(0.f);
    int cb = start;
    for (; cb + 2 <= end; cb += 2) {
        int s0 = src_s[cb], s1 = src_s[cb + 1];
        float p0 = bf2f(p_h[cb]), p1 = bf2f(p_h[cb + 1]);
        ushort4 v0 = *(const ushort4*)(vhh + (size_t)s0 * 32 + ln * 4);
        ushort4 v1 = *(const ushort4*)(vhh + (size_t)s1 * 32 + ln * 4);
        a0[0] += p0 * bf2f(v0.x); a0[1] += p0 * bf2f(v0.y);
        a0[2] += p0 * bf2f(v0.z); a0[3] += p0 * bf2f(v0.w);
        a1[0] += p1 * bf2f(v1.x); a1[1] += p1 * bf2f(v1.y);
        a1[2] += p1 * bf2f(v1.z); a1[3] += p1 * bf2f(v1.w);
    }
    if (cb < end) {
        int s0 = src_s[cb];
        float p0 = bf2f(p_h[cb]);
        ushort4 v0 = *(const ushort4*)(vhh + (size_t)s0 * 32 + ln * 4);
        a0[0] += p0 * bf2f(v0.x); a0[1] += p0 * bf2f(v0.y);
        a0[2] += p0 * bf2f(v0.z); a0[3] += p0 * bf2f(v0.w);
    }
    if (node < NUM_NODES) {
        ushort4 o;
        o.x = f2bf(a0[0] + a1[0]); o.y = f2bf(a0[1] + a1[1]);
        o.z = f2bf(a0[2] + a1[2]); o.w = f2bf(a0[3] + a1[3]);
        *(ushort4*)(aggb + ((size_t)h * NUM_NODES + node) * 32 + ln * 4) = o;
    }
}

extern "C" void kernel_launch(void* const* d_in, const int* in_sizes, int n_in,
                              void* d_out, int out_size, void* d_ws, size_t ws_size,
                              hipStream_t stream) {
    const float* x = (const float*)d_in[0];
    const int* ei = (const int*)d_in[1];
    const int* src_idx = ei;
    const int* dst_idx = ei + NUM_EDGES;
    const float* edge_time = (const float*)d_in[2];
    const float* node_time = (const float*)d_in[3];
    const float* Wq = (const float*)d_in[4];  const float* bq = (const float*)d_in[5];
    const float* Wk = (const float*)d_in[6];  const float* bk = (const float*)d_in[7];
    const float* Wv = (const float*)d_in[8];  const float* bv = (const float*)d_in[9];
    const float* Wt = (const float*)d_in[10]; const float* bt = (const float*)d_in[11];
    const float* Wo = (const float*)d_in[12]; const float* bo = (const float*)d_in[13];
    float* out = (float*)d_out;

    char* w = (char*)d_ws;
    unsigned short* qb = (unsigned short*)w; w += (size_t)NUM_NODES * 256 * 2;  // [8][N][32]
    unsigned short* kb = (unsigned short*)w; w += (size_t)NUM_NODES * 256 * 2;  // [8][N][32]
    unsigned short* vb = (unsigned short*)w; w += (size_t)NUM_NODES * 256 * 2;  // [8][N][32]
    float* scores = (float*)w;      w += (size_t)NUM_EDGES * 8 * 4;             // [8][E]
    unsigned short* pb = (unsigned short*)w; w += (size_t)NUM_EDGES * 8 * 2;    // [8][E] bf16
    unsigned short* aggb = (unsigned short*)w; w += (size_t)NUM_NODES * 256 * 2; // [8][N][32]
    int* src_s = (int*)w;           w += (size_t)NUM_EDGES * 4;
    int* dst_s = (int*)w;           w += (size_t)NUM_EDGES * 4;
    float* et_s = (float*)w;        w += (size_t)NUM_EDGES * 4;
    int* deg = (int*)w;             w += (size_t)NUM_NODES * 4;
    int* offs = (int*)w;            w += (size_t)(NUM_NODES + 1) * 4;
    int* cursor = (int*)w;          w += (size_t)NUM_NODES * 4;
    unsigned* partialmax = (unsigned*)w; w += 1024 * 4;
    float* partialsum = (float*)w;  w += 1024 * 4;
    float* headmax = (float*)w;     w += 8 * 4;
    float* headinv = (float*)w;     w += 8 * 4;
    int* blocksum = (int*)w;        w += 64 * 4;
    int* bcarry = (int*)w;          w += 64 * 4;
    unsigned short* Wtb = (unsigned short*)w; w += (size_t)1024 * 256 * 2;

    hipMemsetAsync(deg, 0, (size_t)NUM_NODES * 4, stream);

    // weight transpose + bf16 cvt (q,k,v,o)
    dim3 gw(16, 4);
    wtrans_kernel<<<gw, 256, 0, stream>>>(Wq, Wk, Wv, Wo, Wtb);

    // CSR by dst (parallel scan)
    deg_kernel<<<(NUM_EDGES + 255) / 256, 256, 0, stream>>>(dst_idx, deg);
    scanA_kernel<<<SCAN_BLOCKS, 1024, 0, stream>>>(deg, offs, blocksum);
    scanB_kernel<<<1, 64, 0, stream>>>(blocksum, bcarry, offs);
    scanC_kernel<<<(NUM_NODES + 255) / 256, 256, 0, stream>>>(offs, bcarry, cursor);
    fill2_kernel<<<(NUM_EDGES + 255) / 256, 256, 0, stream>>>(src_idx, dst_idx, edge_time,
                                                              cursor, src_s, dst_s, et_s);

    // QKV projection -> head-major bf16 q/k/v  (W in registers)
    dim3 gq(130, 3);
    gemm_qkv_reg<<<gq, 512, 0, stream>>>(x, NUM_NODES, Wtb, bq, bk, bv, qb, kb, vb);

    // scores (head-pinned to XCDs) + per-head max
    score3_kernel<<<1024, 256, 0, stream>>>(qb, kb, src_s, dst_s, et_s, node_time,
                                            Wt, bt, scores, partialmax);
    reduce_max2_kernel<<<1, 256, 0, stream>>>(partialmax, headmax);

    // p = exp(s-m) bf16 + global per-head sums
    pexp_kernel<<<1024, 256, 0, stream>>>(scores, headmax, pb, partialsum);
    reduce_psum_kernel<<<1, 256, 0, stream>>>(partialsum, headinv);

    // aggregate (head-pinned, 8-lane groups, vectorized v rows)
    aggregate6_kernel<<<((NUM_NODES + 31) / 32) * 8, 256, 0, stream>>>(
        vb, pb, src_s, offs, aggb);

    // output projection with per-head 1/sum folded into staging (W in registers)
    gemm_out_reg<<<391, 512, 0, stream>>>(
        aggb, NUM_NODES, Wtb + (size_t)768 * 256, bo, headinv, out);
}

// Round 11
// 347.481 us; speedup vs baseline: 1.1855x; 1.0684x over previous
//
#include <hip/hip_runtime.h>
#include <hip/hip_bf16.h>

#define NUM_NODES 50000
#define NUM_EDGES 800000
#define NUM_HEADS 8
#define HEAD_DIM 32
#define SCAN_BLOCKS 49

typedef unsigned short ushort8 __attribute__((ext_vector_type(8)));
typedef float f32x4 __attribute__((ext_vector_type(4)));
typedef __bf16 bf16x8 __attribute__((ext_vector_type(8)));

union BF8 { ushort8 u; bf16x8 b; };

__device__ __forceinline__ unsigned float_to_key(float f) {
    int i = __float_as_int(f);
    return (i >= 0) ? ((unsigned)i | 0x80000000u) : ~(unsigned)i;
}
__device__ __forceinline__ float key_to_float(unsigned u) {
    unsigned b = (u & 0x80000000u) ? (u & 0x7fffffffu) : ~u;
    return __int_as_float((int)b);
}
__device__ __forceinline__ float bf2f(unsigned short u) {
    return __uint_as_float(((unsigned)u) << 16);
}
__device__ __forceinline__ unsigned short f2bf(float f) {
    unsigned u = __float_as_uint(f);
    unsigned r = (u + 0x7fffu + ((u >> 16) & 1u)) >> 16;
    return (unsigned short)r;
}

// ---------- CSR build ----------
__global__ __launch_bounds__(256) void deg_kernel(const int* __restrict__ dst_idx, int* __restrict__ deg) {
    int e = blockIdx.x * 256 + threadIdx.x;
    if (e < NUM_EDGES) atomicAdd(&deg[dst_idx[e]], 1);
}

__global__ __launch_bounds__(1024) void scanA_kernel(
    const int* __restrict__ deg, int* __restrict__ offs, int* __restrict__ blocksum)
{
    __shared__ int buf[1024];
    int tid = threadIdx.x;
    int i = blockIdx.x * 1024 + tid;
    int v = (i < NUM_NODES) ? deg[i] : 0;
    buf[tid] = v;
    __syncthreads();
    for (int off = 1; off < 1024; off <<= 1) {
        int t = (tid >= off) ? buf[tid - off] : 0;
        __syncthreads();
        buf[tid] += t;
        __syncthreads();
    }
    if (i < NUM_NODES) offs[i] = buf[tid] - v;
    if (tid == 1023) blocksum[blockIdx.x] = buf[1023];
}

__global__ __launch_bounds__(64) void scanB_kernel(
    const int* __restrict__ blocksum, int* __restrict__ carry, int* __restrict__ offs)
{
    if (threadIdx.x == 0) {
        int acc = 0;
        for (int b = 0; b < SCAN_BLOCKS; b++) { carry[b] = acc; acc += blocksum[b]; }
        offs[NUM_NODES] = acc;
    }
}

__global__ __launch_bounds__(256) void scanC_kernel(
    int* __restrict__ offs, const int* __restrict__ carry, int* __restrict__ cursor)
{
    int i = blockIdx.x * 256 + threadIdx.x;
    if (i < NUM_NODES) {
        int v = offs[i] + carry[i >> 10];
        offs[i] = v;
        cursor[i] = v;
    }
}

__global__ __launch_bounds__(256) void fill2_kernel(
    const int* __restrict__ src_idx, const int* __restrict__ dst_idx,
    const float* __restrict__ edge_time, int* __restrict__ cursor,
    int* __restrict__ src_s, int* __restrict__ dst_s, float* __restrict__ et_s)
{
    int e = blockIdx.x * 256 + threadIdx.x;
    if (e < NUM_EDGES) {
        int d = dst_idx[e];
        int pos = atomicAdd(&cursor[d], 1);
        src_s[pos] = src_idx[e];
        dst_s[pos] = d;
        et_s[pos] = edge_time[e];
    }
}

// ---------- weight transpose+cvt: Wt[1024 n][256 k] bf16 ----------
__global__ __launch_bounds__(256) void wtrans_kernel(
    const float* __restrict__ Wq, const float* __restrict__ Wk,
    const float* __restrict__ Wv, const float* __restrict__ Wo,
    unsigned short* __restrict__ Wt)
{
    __shared__ float t[64][65];
    int nb = blockIdx.x * 64;
    int kb = blockIdx.y * 64;
    int g = nb >> 8;
    const float* W = (g == 0) ? Wq : (g == 1) ? Wk : (g == 2) ? Wv : Wo;
    int n0 = nb & 255;
    int tx = threadIdx.x & 63;
    int ty = threadIdx.x >> 6;
#pragma unroll
    for (int i = 0; i < 16; i++) {
        int k = i * 4 + ty;
        t[tx][k] = W[(size_t)(kb + k) * 256 + n0 + tx];
    }
    __syncthreads();
#pragma unroll
    for (int i = 0; i < 16; i++) {
        int n = i * 4 + ty;
        Wt[(size_t)(nb + n) * 256 + kb + tx] = f2bf(t[n][tx]);
    }
}

// ---------- pack W into MFMA fragment order: [g][cb][nf][c2][lane][8] ----------
__global__ __launch_bounds__(256) void wpack_kernel(
    const unsigned short* __restrict__ Wt, unsigned short* __restrict__ Wpk)
{
    int gid = blockIdx.x * 256 + threadIdx.x;   // 0..32767
    int lane = gid & 63;
    int fragidx = gid >> 6;                     // 0..511
    int c2 = fragidx & 7;
    int nf = (fragidx >> 3) & 3;
    int cb = (fragidx >> 5) & 3;
    int g = fragidx >> 7;
    int l16 = lane & 15;
    int kg = lane >> 4;
    int n_col = g * 256 + cb * 64 + nf * 16 + l16;
    int k0 = c2 * 32 + kg * 8;
    ushort8 v = *(const ushort8*)(Wt + (size_t)n_col * 256 + k0);
    *(ushort8*)(Wpk + (size_t)gid * 8) = v;
}

// ---------- QKV GEMM via MFMA, 64-row tiles, packed-W; head-major out ----------
__global__ __launch_bounds__(256) void gemm_qkv_mfma6(
    const float* __restrict__ A, int M,
    const unsigned short* __restrict__ Wpk,
    const float* __restrict__ b0, const float* __restrict__ b1, const float* __restrict__ b2,
    unsigned short* __restrict__ O0, unsigned short* __restrict__ O1, unsigned short* __restrict__ O2)
{
    __shared__ unsigned short As[64 * 256];   // 32 KB, 16B-chunk swizzle: c ^= (row&7)
    int tid = threadIdx.x;
    int rowbase = blockIdx.x * 64;

    // stage A -> bf16 LDS once
    {
        int rsub = tid >> 6;          // 0..3
        int c4 = (tid & 63) * 4;
        int cchunk = (tid & 63) >> 1;
        int sub = (tid & 1);
#pragma unroll
        for (int it = 0; it < 16; it++) {
            int row = it * 4 + rsub;
            int grow = rowbase + row;
            float4 av = make_float4(0.f, 0.f, 0.f, 0.f);
            if (grow < M) av = *(const float4*)(A + (size_t)grow * 256 + c4);
            ushort4 o;
            o.x = f2bf(av.x); o.y = f2bf(av.y); o.z = f2bf(av.z); o.w = f2bf(av.w);
            unsigned byte = row * 512 + ((unsigned)(cchunk ^ (row & 7)) << 4) + sub * 8;
            *(ushort4*)((char*)As + byte) = o;
        }
    }
    __syncthreads();

    int lane = tid & 63;
    int wid = tid >> 6;      // wave owns cols [wid*64, wid*64+64) within p's 256
    int l16 = lane & 15;
    int kg = lane >> 4;

#pragma unroll
    for (int p = 0; p < 3; p++) {      // q, k, v
        const float* bias = (p == 0) ? b0 : (p == 1) ? b1 : b2;
        unsigned short* O = (p == 0) ? O0 : (p == 1) ? O1 : O2;

        f32x4 acc[4][4];
#pragma unroll
        for (int m = 0; m < 4; m++)
#pragma unroll
            for (int n = 0; n < 4; n++) acc[m][n] = (f32x4)(0.0f);

        // packed W base for (g=p, cb=wid): frag (nf, c2) at ((nf*8+c2)*64+lane)*8
        const ushort8* wbase = (const ushort8*)(Wpk + ((size_t)(p * 4 + wid) * 2048 + lane) * 8);

#pragma unroll
        for (int c2 = 0; c2 < 8; c2++) {
            bf16x8 wfr[4];
#pragma unroll
            for (int n = 0; n < 4; n++) {
                BF8 t; t.u = wbase[(n * 8 + c2) * 64];
                wfr[n] = t.b;
            }
            bf16x8 afr[4];
#pragma unroll
            for (int m = 0; m < 4; m++) {
                int row = m * 16 + l16;
                int cchunk = (c2 * 4 + kg) ^ (row & 7);
                BF8 t;
                t.u = *(const ushort8*)((const char*)As + row * 512 + (cchunk << 4));
                afr[m] = t.b;
            }
#pragma unroll
            for (int m = 0; m < 4; m++)
#pragma unroll
                for (int n = 0; n < 4; n++)
                    acc[m][n] = __builtin_amdgcn_mfma_f32_16x16x32_bf16(wfr[n], afr[m], acc[m][n], 0, 0, 0);
        }

#pragma unroll
        for (int m = 0; m < 4; m++) {
            int node = rowbase + m * 16 + l16;
            if (node >= M) continue;
#pragma unroll
            for (int n = 0; n < 4; n++) {
                int lc = wid * 64 + n * 16 + kg * 4;
                float4 bv = *(const float4*)(bias + lc);
                ushort4 o;
                o.x = f2bf(acc[m][n][0] + bv.x);
                o.y = f2bf(acc[m][n][1] + bv.y);
                o.z = f2bf(acc[m][n][2] + bv.z);
                o.w = f2bf(acc[m][n][3] + bv.w);
                int hh = lc >> 5, dd = lc & 31;
                *(ushort4*)(O + ((size_t)hh * NUM_NODES + node) * 32 + dd) = o;
            }
        }
    }
}

// ---------- output GEMM, 64-row tiles, packed-W; per-head scale in staging ----------
__global__ __launch_bounds__(256) void gemm_out_mfma6(
    const unsigned short* __restrict__ aggb, int M,
    const unsigned short* __restrict__ Wpk,     // g=3 region base
    const float* __restrict__ bias, const float* __restrict__ kscale,
    float* __restrict__ C)
{
    __shared__ unsigned short As[64 * 256];
    int tid = threadIdx.x;
    int rowbase = blockIdx.x * 64;

    {
        int rsub = tid >> 6;
        int c4 = (tid & 63) * 4;
        int cchunk = (tid & 63) >> 1;
        int sub = (tid & 1);
        int hh = c4 >> 5, dd = c4 & 31;
        float ks = kscale[hh];
#pragma unroll
        for (int it = 0; it < 16; it++) {
            int row = it * 4 + rsub;
            int grow = rowbase + row;
            ushort4 av = make_ushort4(0, 0, 0, 0);
            if (grow < M) av = *(const ushort4*)(aggb + ((size_t)hh * NUM_NODES + grow) * 32 + dd);
            ushort4 o;
            o.x = f2bf(bf2f(av.x) * ks); o.y = f2bf(bf2f(av.y) * ks);
            o.z = f2bf(bf2f(av.z) * ks); o.w = f2bf(bf2f(av.w) * ks);
            unsigned byte = row * 512 + ((unsigned)(cchunk ^ (row & 7)) << 4) + sub * 8;
            *(ushort4*)((char*)As + byte) = o;
        }
    }
    __syncthreads();

    int lane = tid & 63;
    int wid = tid >> 6;
    int l16 = lane & 15;
    int kg = lane >> 4;

    f32x4 acc[4][4];
#pragma unroll
    for (int m = 0; m < 4; m++)
#pragma unroll
        for (int n = 0; n < 4; n++) acc[m][n] = (f32x4)(0.0f);

    const ushort8* wbase = (const ushort8*)(Wpk + ((size_t)wid * 2048 + lane) * 8);

#pragma unroll
    for (int c2 = 0; c2 < 8; c2++) {
        bf16x8 wfr[4];
#pragma unroll
        for (int n = 0; n < 4; n++) {
            BF8 t; t.u = wbase[(n * 8 + c2) * 64];
            wfr[n] = t.b;
        }
        bf16x8 afr[4];
#pragma unroll
        for (int m = 0; m < 4; m++) {
            int row = m * 16 + l16;
            int cchunk = (c2 * 4 + kg) ^ (row & 7);
            BF8 t;
            t.u = *(const ushort8*)((const char*)As + row * 512 + (cchunk << 4));
            afr[m] = t.b;
        }
#pragma unroll
        for (int m = 0; m < 4; m++)
#pragma unroll
            for (int n = 0; n < 4; n++)
                acc[m][n] = __builtin_amdgcn_mfma_f32_16x16x32_bf16(wfr[n], afr[m], acc[m][n], 0, 0, 0);
    }

#pragma unroll
    for (int m = 0; m < 4; m++) {
        int node = rowbase + m * 16 + l16;
        if (node >= M) continue;
#pragma unroll
        for (int n = 0; n < 4; n++) {
            int col = wid * 64 + n * 16 + kg * 4;
            float4 bv = *(const float4*)(bias + col);
            float4 o;
            o.x = acc[m][n][0] + bv.x;
            o.y = acc[m][n][1] + bv.y;
            o.z = acc[m][n][2] + bv.z;
            o.w = acc[m][n][3] + bv.w;
            *(float4*)(C + (size_t)node * 256 + col) = o;
        }
    }
}

// ---------- scores, head-pinned (h = blockIdx & 7 -> XCD), head-major output ----------
__global__ __launch_bounds__(256) void score3_kernel(
    const unsigned short* __restrict__ qh, const unsigned short* __restrict__ kh,
    const int* __restrict__ src_s, const int* __restrict__ dst_s,
    const float* __restrict__ et_s, const float* __restrict__ node_time,
    const float* __restrict__ Wt, const float* __restrict__ bt,
    float* __restrict__ scores, unsigned* __restrict__ partialmax)
{
    __shared__ unsigned sm;
    int tid = threadIdx.x;
    if (tid == 0) sm = 0u;
    __syncthreads();
    int h = blockIdx.x & 7;
    int blk = blockIdx.x >> 3;               // 0..127
    float wt0 = Wt[h], wt1 = Wt[8 + h], btv = bt[h];
    const unsigned short* qhh = qh + (size_t)h * NUM_NODES * 32;
    const unsigned short* khh = kh + (size_t)h * NUM_NODES * 32;
    float* sc_h = scores + (size_t)h * NUM_EDGES;
    unsigned mykey = 0u;
    for (int pos = blk * 256 + tid; pos < NUM_EDGES; pos += 128 * 256) {
        int s = src_s[pos], d = dst_s[pos];
        const ushort8* qp = (const ushort8*)(qhh + (size_t)d * 32);
        const ushort8* kp = (const ushort8*)(khh + (size_t)s * 32);
        float dotv = 0.f;
#pragma unroll
        for (int i = 0; i < 4; i++) {
            ushort8 a = qp[i], b = kp[i];
#pragma unroll
            for (int j = 0; j < 8; j++) dotv += bf2f(a[j]) * bf2f(b[j]);
        }
        float td = et_s[pos] - node_time[d];
        float tf0 = (td > 0.f) ? 1.f : ((td < 0.f) ? -1.f : 0.f);
        float tf1 = log1pf(fabsf(td) * (1.f / 3600.f));
        float sc = dotv * 0.17677669529663687f + (tf0 * wt0 + tf1 * wt1 + btv);
        sc_h[pos] = sc;
        unsigned kkey = float_to_key(sc);
        mykey = (kkey > mykey) ? kkey : mykey;
    }
#pragma unroll
    for (int off = 32; off > 0; off >>= 1) {
        unsigned o = __shfl_xor(mykey, off, 64);
        mykey = (o > mykey) ? o : mykey;
    }
    if ((tid & 63) == 0) atomicMax(&sm, mykey);
    __syncthreads();
    if (tid == 0) partialmax[blockIdx.x] = sm;
}

// partialmax[1024], entry i belongs to head i&7
__global__ __launch_bounds__(256) void reduce_max2_kernel(
    const unsigned* __restrict__ partialmax, float* __restrict__ headmax)
{
    int tid = threadIdx.x;
    int h = tid >> 5, lane = tid & 31;
    unsigned m = 0u;
#pragma unroll
    for (int k = 0; k < 4; k++) {
        unsigned v = partialmax[(lane + 32 * k) * 8 + h];
        m = (v > m) ? v : m;
    }
    for (int off = 16; off > 0; off >>= 1) {
        unsigned o = __shfl_down(m, off, 32);
        m = (o > m) ? o : m;
    }
    if (lane == 0) headmax[h] = key_to_float(m);
}

// ---------- p = exp(s - m) -> bf16, + global per-head sum partials ----------
__global__ __launch_bounds__(256) void pexp_kernel(
    const float* __restrict__ scores, const float* __restrict__ headmax,
    unsigned short* __restrict__ pb, float* __restrict__ partialsum)
{
    __shared__ float ssum;
    int tid = threadIdx.x;
    if (tid == 0) ssum = 0.f;
    __syncthreads();
    int h = blockIdx.x & 7;
    int blk = blockIdx.x >> 3;
    float m = headmax[h];
    const float* sc_h = scores + (size_t)h * NUM_EDGES;
    unsigned short* p_h = pb + (size_t)h * NUM_EDGES;
    float s = 0.f;
    for (int pos = blk * 256 + tid; pos < NUM_EDGES; pos += 128 * 256) {
        float p = __expf(sc_h[pos] - m);
        p_h[pos] = f2bf(p);
        s += p;
    }
#pragma unroll
    for (int off = 32; off > 0; off >>= 1) s += __shfl_xor(s, off, 64);
    if ((tid & 63) == 0) atomicAdd(&ssum, s);
    __syncthreads();
    if (tid == 0) partialsum[blockIdx.x] = ssum;
}

// partialsum[1024], entry i belongs to head i&7
__global__ __launch_bounds__(256) void reduce_psum_kernel(
    const float* __restrict__ partialsum, float* __restrict__ headinv)
{
    int tid = threadIdx.x;
    int h = tid >> 5, lane = tid & 31;
    float s = 0.f;
#pragma unroll
    for (int k = 0; k < 4; k++) s += partialsum[(lane + 32 * k) * 8 + h];
    for (int off = 16; off > 0; off >>= 1) s += __shfl_down(s, off, 32);
    if (lane == 0) headinv[h] = 1.f / s;
}

// ---------- aggregate: head-pinned; 8-lane group per node, lane = 4 dims ----------
__global__ __launch_bounds__(256) void aggregate6_kernel(
    const unsigned short* __restrict__ vh, const unsigned short* __restrict__ pb,
    const int* __restrict__ src_s, const int* __restrict__ offs,
    unsigned short* __restrict__ aggb)
{
    int tid = threadIdx.x;
    int h = blockIdx.x & 7;
    int chunk = blockIdx.x >> 3;
    int g = tid >> 3;            // 0..31 node within chunk
    int ln = tid & 7;            // 4-dim slot
    int node = chunk * 32 + g;
    const unsigned short* p_h = pb + (size_t)h * NUM_EDGES;
    const unsigned short* vhh = vh + (size_t)h * NUM_NODES * 32;
    int start = 0, end = 0;
    if (node < NUM_NODES) { start = offs[node]; end = offs[node + 1]; }
    f32x4 a0 = (f32x4)(0.f), a1 = (f32x4)(0.f);
    int cb = start;
    for (; cb + 2 <= end; cb += 2) {
        int s0 = src_s[cb], s1 = src_s[cb + 1];
        float p0 = bf2f(p_h[cb]), p1 = bf2f(p_h[cb + 1]);
        ushort4 v0 = *(const ushort4*)(vhh + (size_t)s0 * 32 + ln * 4);
        ushort4 v1 = *(const ushort4*)(vhh + (size_t)s1 * 32 + ln * 4);
        a0[0] += p0 * bf2f(v0.x); a0[1] += p0 * bf2f(v0.y);
        a0[2] += p0 * bf2f(v0.z); a0[3] += p0 * bf2f(v0.w);
        a1[0] += p1 * bf2f(v1.x); a1[1] += p1 * bf2f(v1.y);
        a1[2] += p1 * bf2f(v1.z); a1[3] += p1 * bf2f(v1.w);
    }
    if (cb < end) {
        int s0 = src_s[cb];
        float p0 = bf2f(p_h[cb]);
        ushort4 v0 = *(const ushort4*)(vhh + (size_t)s0 * 32 + ln * 4);
        a0[0] += p0 * bf2f(v0.x); a0[1] += p0 * bf2f(v0.y);
        a0[2] += p0 * bf2f(v0.z); a0[3] += p0 * bf2f(v0.w);
    }
    if (node < NUM_NODES) {
        ushort4 o;
        o.x = f2bf(a0[0] + a1[0]); o.y = f2bf(a0[1] + a1[1]);
        o.z = f2bf(a0[2] + a1[2]); o.w = f2bf(a0[3] + a1[3]);
        *(ushort4*)(aggb + ((size_t)h * NUM_NODES + node) * 32 + ln * 4) = o;
    }
}

extern "C" void kernel_launch(void* const* d_in, const int* in_sizes, int n_in,
                              void* d_out, int out_size, void* d_ws, size_t ws_size,
                              hipStream_t stream) {
    const float* x = (const float*)d_in[0];
    const int* ei = (const int*)d_in[1];
    const int* src_idx = ei;
    const int* dst_idx = ei + NUM_EDGES;
    const float* edge_time = (const float*)d_in[2];
    const float* node_time = (const float*)d_in[3];
    const float* Wq = (const float*)d_in[4];  const float* bq = (const float*)d_in[5];
    const float* Wk = (const float*)d_in[6];  const float* bk = (const float*)d_in[7];
    const float* Wv = (const float*)d_in[8];  const float* bv = (const float*)d_in[9];
    const float* Wt = (const float*)d_in[10]; const float* bt = (const float*)d_in[11];
    const float* Wo = (const float*)d_in[12]; const float* bo = (const float*)d_in[13];
    float* out = (float*)d_out;

    char* w = (char*)d_ws;
    unsigned short* qb = (unsigned short*)w; w += (size_t)NUM_NODES * 256 * 2;  // [8][N][32]
    unsigned short* kb = (unsigned short*)w; w += (size_t)NUM_NODES * 256 * 2;  // [8][N][32]
    unsigned short* vb = (unsigned short*)w; w += (size_t)NUM_NODES * 256 * 2;  // [8][N][32]
    float* scores = (float*)w;      w += (size_t)NUM_EDGES * 8 * 4;             // [8][E]
    unsigned short* pb = (unsigned short*)w; w += (size_t)NUM_EDGES * 8 * 2;    // [8][E] bf16
    unsigned short* aggb = (unsigned short*)w; w += (size_t)NUM_NODES * 256 * 2; // [8][N][32]
    int* src_s = (int*)w;           w += (size_t)NUM_EDGES * 4;
    int* dst_s = (int*)w;           w += (size_t)NUM_EDGES * 4;
    float* et_s = (float*)w;        w += (size_t)NUM_EDGES * 4;
    int* deg = (int*)w;             w += (size_t)NUM_NODES * 4;
    int* offs = (int*)w;            w += (size_t)(NUM_NODES + 1) * 4;
    int* cursor = (int*)w;          w += (size_t)NUM_NODES * 4;
    unsigned* partialmax = (unsigned*)w; w += 1024 * 4;
    float* partialsum = (float*)w;  w += 1024 * 4;
    float* headmax = (float*)w;     w += 8 * 4;
    float* headinv = (float*)w;     w += 8 * 4;
    int* blocksum = (int*)w;        w += 64 * 4;
    int* bcarry = (int*)w;          w += 64 * 4;
    unsigned short* Wtb = (unsigned short*)w; w += (size_t)1024 * 256 * 2;
    unsigned short* Wpk = (unsigned short*)w; w += (size_t)1024 * 256 * 2;      // fragment-packed

    hipMemsetAsync(deg, 0, (size_t)NUM_NODES * 4, stream);

    // weight transpose + bf16 cvt (q,k,v,o), then fragment-pack
    dim3 gw(16, 4);
    wtrans_kernel<<<gw, 256, 0, stream>>>(Wq, Wk, Wv, Wo, Wtb);
    wpack_kernel<<<128, 256, 0, stream>>>(Wtb, Wpk);

    // CSR by dst (parallel scan)
    deg_kernel<<<(NUM_EDGES + 255) / 256, 256, 0, stream>>>(dst_idx, deg);
    scanA_kernel<<<SCAN_BLOCKS, 1024, 0, stream>>>(deg, offs, blocksum);
    scanB_kernel<<<1, 64, 0, stream>>>(blocksum, bcarry, offs);
    scanC_kernel<<<(NUM_NODES + 255) / 256, 256, 0, stream>>>(offs, bcarry, cursor);
    fill2_kernel<<<(NUM_EDGES + 255) / 256, 256, 0, stream>>>(src_idx, dst_idx, edge_time,
                                                              cursor, src_s, dst_s, et_s);

    // QKV projection -> head-major bf16 q/k/v  (packed-W, A staged once)
    gemm_qkv_mfma6<<<(NUM_NODES + 63) / 64, 256, 0, stream>>>(
        x, NUM_NODES, Wpk, bq, bk, bv, qb, kb, vb);

    // scores (head-pinned to XCDs) + per-head max
    score3_kernel<<<1024, 256, 0, stream>>>(qb, kb, src_s, dst_s, et_s, node_time,
                                            Wt, bt, scores, partialmax);
    reduce_max2_kernel<<<1, 256, 0, stream>>>(partialmax, headmax);

    // p = exp(s-m) bf16 + global per-head sums
    pexp_kernel<<<1024, 256, 0, stream>>>(scores, headmax, pb, partialsum);
    reduce_psum_kernel<<<1, 256, 0, stream>>>(partialsum, headinv);

    // aggregate (head-pinned, 8-lane groups, vectorized v rows)
    aggregate6_kernel<<<((NUM_NODES + 31) / 32) * 8, 256, 0, stream>>>(
        vb, pb, src_s, offs, aggb);

    // output projection with per-head 1/sum folded into staging (packed-W)
    gemm_out_mfma6<<<(NUM_NODES + 63) / 64, 256, 0, stream>>>(
        aggb, NUM_NODES, Wpk + (size_t)768 * 256, bo, headinv, out);
}

// Round 12
// 331.412 us; speedup vs baseline: 1.2430x; 1.0485x over previous
//
#include <hip/hip_runtime.h>
#include <hip/hip_bf16.h>

#define NUM_NODES 50000
#define NUM_EDGES 800000
#define NUM_HEADS 8
#define HEAD_DIM 32
#define SCAN_BLOCKS 49
#define NCHUNK32 1563   // ceil(50000/32)

typedef unsigned short ushort8 __attribute__((ext_vector_type(8)));
typedef float f32x4 __attribute__((ext_vector_type(4)));
typedef __bf16 bf16x8 __attribute__((ext_vector_type(8)));

union BF8 { ushort8 u; bf16x8 b; };

__device__ __forceinline__ unsigned float_to_key(float f) {
    int i = __float_as_int(f);
    return (i >= 0) ? ((unsigned)i | 0x80000000u) : ~(unsigned)i;
}
__device__ __forceinline__ float key_to_float(unsigned u) {
    unsigned b = (u & 0x80000000u) ? (u & 0x7fffffffu) : ~u;
    return __int_as_float((int)b);
}
__device__ __forceinline__ float bf2f(unsigned short u) {
    return __uint_as_float(((unsigned)u) << 16);
}
__device__ __forceinline__ unsigned short f2bf(float f) {
    unsigned u = __float_as_uint(f);
    unsigned r = (u + 0x7fffu + ((u >> 16) & 1u)) >> 16;
    return (unsigned short)r;
}

// ---------- CSR build ----------
__global__ __launch_bounds__(256) void deg_kernel(const int* __restrict__ dst_idx, int* __restrict__ deg) {
    int e = blockIdx.x * 256 + threadIdx.x;
    if (e < NUM_EDGES) atomicAdd(&deg[dst_idx[e]], 1);
}

__global__ __launch_bounds__(1024) void scanA_kernel(
    const int* __restrict__ deg, int* __restrict__ offs, int* __restrict__ blocksum)
{
    __shared__ int buf[1024];
    int tid = threadIdx.x;
    int i = blockIdx.x * 1024 + tid;
    int v = (i < NUM_NODES) ? deg[i] : 0;
    buf[tid] = v;
    __syncthreads();
    for (int off = 1; off < 1024; off <<= 1) {
        int t = (tid >= off) ? buf[tid - off] : 0;
        __syncthreads();
        buf[tid] += t;
        __syncthreads();
    }
    if (i < NUM_NODES) offs[i] = buf[tid] - v;
    if (tid == 1023) blocksum[blockIdx.x] = buf[1023];
}

__global__ __launch_bounds__(64) void scanB_kernel(
    const int* __restrict__ blocksum, int* __restrict__ carry, int* __restrict__ offs)
{
    if (threadIdx.x == 0) {
        int acc = 0;
        for (int b = 0; b < SCAN_BLOCKS; b++) { carry[b] = acc; acc += blocksum[b]; }
        offs[NUM_NODES] = acc;
    }
}

__global__ __launch_bounds__(256) void scanC_kernel(
    int* __restrict__ offs, const int* __restrict__ carry, int* __restrict__ cursor)
{
    int i = blockIdx.x * 256 + threadIdx.x;
    if (i < NUM_NODES) {
        int v = offs[i] + carry[i >> 10];
        offs[i] = v;
        cursor[i] = v;
    }
}

__global__ __launch_bounds__(256) void fill2_kernel(
    const int* __restrict__ src_idx, const int* __restrict__ dst_idx,
    const float* __restrict__ edge_time, int* __restrict__ cursor,
    int* __restrict__ src_s, int* __restrict__ dst_s, float* __restrict__ et_s)
{
    int e = blockIdx.x * 256 + threadIdx.x;
    if (e < NUM_EDGES) {
        int d = dst_idx[e];
        int pos = atomicAdd(&cursor[d], 1);
        src_s[pos] = src_idx[e];
        dst_s[pos] = d;
        et_s[pos] = edge_time[e];
    }
}

// ---------- weight transpose+cvt: Wt[1024 n][256 k] bf16 ----------
__global__ __launch_bounds__(256) void wtrans_kernel(
    const float* __restrict__ Wq, const float* __restrict__ Wk,
    const float* __restrict__ Wv, const float* __restrict__ Wo,
    unsigned short* __restrict__ Wt)
{
    __shared__ float t[64][65];
    int nb = blockIdx.x * 64;
    int kb = blockIdx.y * 64;
    int g = nb >> 8;
    const float* W = (g == 0) ? Wq : (g == 1) ? Wk : (g == 2) ? Wv : Wo;
    int n0 = nb & 255;
    int tx = threadIdx.x & 63;
    int ty = threadIdx.x >> 6;
#pragma unroll
    for (int i = 0; i < 16; i++) {
        int k = i * 4 + ty;
        t[tx][k] = W[(size_t)(kb + k) * 256 + n0 + tx];
    }
    __syncthreads();
#pragma unroll
    for (int i = 0; i < 16; i++) {
        int n = i * 4 + ty;
        Wt[(size_t)(nb + n) * 256 + kb + tx] = f2bf(t[n][tx]);
    }
}

// ---------- pack W into MFMA fragment order: [g][cb][nf][c2][lane][8] ----------
__global__ __launch_bounds__(256) void wpack_kernel(
    const unsigned short* __restrict__ Wt, unsigned short* __restrict__ Wpk)
{
    int gid = blockIdx.x * 256 + threadIdx.x;   // 0..32767
    int lane = gid & 63;
    int fragidx = gid >> 6;                     // 0..511
    int c2 = fragidx & 7;
    int nf = (fragidx >> 3) & 3;
    int cb = (fragidx >> 5) & 3;
    int g = fragidx >> 7;
    int l16 = lane & 15;
    int kg = lane >> 4;
    int n_col = g * 256 + cb * 64 + nf * 16 + l16;
    int k0 = c2 * 32 + kg * 8;
    ushort8 v = *(const ushort8*)(Wt + (size_t)n_col * 256 + k0);
    *(ushort8*)(Wpk + (size_t)gid * 8) = v;
}

// ---------- QKV GEMM via MFMA, 64-row tiles, packed-W; head-major out ----------
__global__ __launch_bounds__(256) void gemm_qkv_mfma6(
    const float* __restrict__ A, int M,
    const unsigned short* __restrict__ Wpk,
    const float* __restrict__ b0, const float* __restrict__ b1, const float* __restrict__ b2,
    unsigned short* __restrict__ O0, unsigned short* __restrict__ O1, unsigned short* __restrict__ O2)
{
    __shared__ unsigned short As[64 * 256];   // 32 KB, 16B-chunk swizzle: c ^= (row&7)
    int tid = threadIdx.x;
    int rowbase = blockIdx.x * 64;

    {
        int rsub = tid >> 6;
        int c4 = (tid & 63) * 4;
        int cchunk = (tid & 63) >> 1;
        int sub = (tid & 1);
#pragma unroll
        for (int it = 0; it < 16; it++) {
            int row = it * 4 + rsub;
            int grow = rowbase + row;
            float4 av = make_float4(0.f, 0.f, 0.f, 0.f);
            if (grow < M) av = *(const float4*)(A + (size_t)grow * 256 + c4);
            ushort4 o;
            o.x = f2bf(av.x); o.y = f2bf(av.y); o.z = f2bf(av.z); o.w = f2bf(av.w);
            unsigned byte = row * 512 + ((unsigned)(cchunk ^ (row & 7)) << 4) + sub * 8;
            *(ushort4*)((char*)As + byte) = o;
        }
    }
    __syncthreads();

    int lane = tid & 63;
    int wid = tid >> 6;
    int l16 = lane & 15;
    int kg = lane >> 4;

#pragma unroll
    for (int p = 0; p < 3; p++) {
        const float* bias = (p == 0) ? b0 : (p == 1) ? b1 : b2;
        unsigned short* O = (p == 0) ? O0 : (p == 1) ? O1 : O2;

        f32x4 acc[4][4];
#pragma unroll
        for (int m = 0; m < 4; m++)
#pragma unroll
            for (int n = 0; n < 4; n++) acc[m][n] = (f32x4)(0.0f);

        const ushort8* wbase = (const ushort8*)(Wpk + ((size_t)(p * 4 + wid) * 2048 + lane) * 8);

#pragma unroll
        for (int c2 = 0; c2 < 8; c2++) {
            bf16x8 wfr[4];
#pragma unroll
            for (int n = 0; n < 4; n++) {
                BF8 t; t.u = wbase[(n * 8 + c2) * 64];
                wfr[n] = t.b;
            }
            bf16x8 afr[4];
#pragma unroll
            for (int m = 0; m < 4; m++) {
                int row = m * 16 + l16;
                int cchunk = (c2 * 4 + kg) ^ (row & 7);
                BF8 t;
                t.u = *(const ushort8*)((const char*)As + row * 512 + (cchunk << 4));
                afr[m] = t.b;
            }
#pragma unroll
            for (int m = 0; m < 4; m++)
#pragma unroll
                for (int n = 0; n < 4; n++)
                    acc[m][n] = __builtin_amdgcn_mfma_f32_16x16x32_bf16(wfr[n], afr[m], acc[m][n], 0, 0, 0);
        }

#pragma unroll
        for (int m = 0; m < 4; m++) {
            int node = rowbase + m * 16 + l16;
            if (node >= M) continue;
#pragma unroll
            for (int n = 0; n < 4; n++) {
                int lc = wid * 64 + n * 16 + kg * 4;
                float4 bv = *(const float4*)(bias + lc);
                ushort4 o;
                o.x = f2bf(acc[m][n][0] + bv.x);
                o.y = f2bf(acc[m][n][1] + bv.y);
                o.z = f2bf(acc[m][n][2] + bv.z);
                o.w = f2bf(acc[m][n][3] + bv.w);
                int hh = lc >> 5, dd = lc & 31;
                *(ushort4*)(O + ((size_t)hh * NUM_NODES + node) * 32 + dd) = o;
            }
        }
    }
}

// ---------- output GEMM, 64-row tiles, packed-W; per-head scale in staging ----------
__global__ __launch_bounds__(256) void gemm_out_mfma6(
    const unsigned short* __restrict__ aggb, int M,
    const unsigned short* __restrict__ Wpk,
    const float* __restrict__ bias, const float* __restrict__ kscale,
    float* __restrict__ C)
{
    __shared__ unsigned short As[64 * 256];
    int tid = threadIdx.x;
    int rowbase = blockIdx.x * 64;

    {
        int rsub = tid >> 6;
        int c4 = (tid & 63) * 4;
        int cchunk = (tid & 63) >> 1;
        int sub = (tid & 1);
        int hh = c4 >> 5, dd = c4 & 31;
        float ks = kscale[hh];
#pragma unroll
        for (int it = 0; it < 16; it++) {
            int row = it * 4 + rsub;
            int grow = rowbase + row;
            ushort4 av = make_ushort4(0, 0, 0, 0);
            if (grow < M) av = *(const ushort4*)(aggb + ((size_t)hh * NUM_NODES + grow) * 32 + dd);
            ushort4 o;
            o.x = f2bf(bf2f(av.x) * ks); o.y = f2bf(bf2f(av.y) * ks);
            o.z = f2bf(bf2f(av.z) * ks); o.w = f2bf(bf2f(av.w) * ks);
            unsigned byte = row * 512 + ((unsigned)(cchunk ^ (row & 7)) << 4) + sub * 8;
            *(ushort4*)((char*)As + byte) = o;
        }
    }
    __syncthreads();

    int lane = tid & 63;
    int wid = tid >> 6;
    int l16 = lane & 15;
    int kg = lane >> 4;

    f32x4 acc[4][4];
#pragma unroll
    for (int m = 0; m < 4; m++)
#pragma unroll
        for (int n = 0; n < 4; n++) acc[m][n] = (f32x4)(0.0f);

    const ushort8* wbase = (const ushort8*)(Wpk + ((size_t)wid * 2048 + lane) * 8);

#pragma unroll
    for (int c2 = 0; c2 < 8; c2++) {
        bf16x8 wfr[4];
#pragma unroll
        for (int n = 0; n < 4; n++) {
            BF8 t; t.u = wbase[(n * 8 + c2) * 64];
            wfr[n] = t.b;
        }
        bf16x8 afr[4];
#pragma unroll
        for (int m = 0; m < 4; m++) {
            int row = m * 16 + l16;
            int cchunk = (c2 * 4 + kg) ^ (row & 7);
            BF8 t;
            t.u = *(const ushort8*)((const char*)As + row * 512 + (cchunk << 4));
            afr[m] = t.b;
        }
#pragma unroll
        for (int m = 0; m < 4; m++)
#pragma unroll
            for (int n = 0; n < 4; n++)
                acc[m][n] = __builtin_amdgcn_mfma_f32_16x16x32_bf16(wfr[n], afr[m], acc[m][n], 0, 0, 0);
    }

#pragma unroll
    for (int m = 0; m < 4; m++) {
        int node = rowbase + m * 16 + l16;
        if (node >= M) continue;
#pragma unroll
        for (int n = 0; n < 4; n++) {
            int col = wid * 64 + n * 16 + kg * 4;
            float4 bv = *(const float4*)(bias + col);
            float4 o;
            o.x = acc[m][n][0] + bv.x;
            o.y = acc[m][n][1] + bv.y;
            o.z = acc[m][n][2] + bv.z;
            o.w = acc[m][n][3] + bv.w;
            *(float4*)(C + (size_t)node * 256 + col) = o;
        }
    }
}

// ---------- scores, head-pinned (h = blockIdx & 7 -> XCD), head-major output ----------
__global__ __launch_bounds__(256) void score3_kernel(
    const unsigned short* __restrict__ qh, const unsigned short* __restrict__ kh,
    const int* __restrict__ src_s, const int* __restrict__ dst_s,
    const float* __restrict__ et_s, const float* __restrict__ node_time,
    const float* __restrict__ Wt, const float* __restrict__ bt,
    float* __restrict__ scores, unsigned* __restrict__ partialmax)
{
    __shared__ unsigned sm;
    int tid = threadIdx.x;
    if (tid == 0) sm = 0u;
    __syncthreads();
    int h = blockIdx.x & 7;
    int blk = blockIdx.x >> 3;               // 0..127
    float wt0 = Wt[h], wt1 = Wt[8 + h], btv = bt[h];
    const unsigned short* qhh = qh + (size_t)h * NUM_NODES * 32;
    const unsigned short* khh = kh + (size_t)h * NUM_NODES * 32;
    float* sc_h = scores + (size_t)h * NUM_EDGES;
    unsigned mykey = 0u;
    for (int pos = blk * 256 + tid; pos < NUM_EDGES; pos += 128 * 256) {
        int s = src_s[pos], d = dst_s[pos];
        const ushort8* qp = (const ushort8*)(qhh + (size_t)d * 32);
        const ushort8* kp = (const ushort8*)(khh + (size_t)s * 32);
        float dotv = 0.f;
#pragma unroll
        for (int i = 0; i < 4; i++) {
            ushort8 a = qp[i], b = kp[i];
#pragma unroll
            for (int j = 0; j < 8; j++) dotv += bf2f(a[j]) * bf2f(b[j]);
        }
        float td = et_s[pos] - node_time[d];
        float tf0 = (td > 0.f) ? 1.f : ((td < 0.f) ? -1.f : 0.f);
        float tf1 = log1pf(fabsf(td) * (1.f / 3600.f));
        float sc = dotv * 0.17677669529663687f + (tf0 * wt0 + tf1 * wt1 + btv);
        sc_h[pos] = sc;
        unsigned kkey = float_to_key(sc);
        mykey = (kkey > mykey) ? kkey : mykey;
    }
#pragma unroll
    for (int off = 32; off > 0; off >>= 1) {
        unsigned o = __shfl_xor(mykey, off, 64);
        mykey = (o > mykey) ? o : mykey;
    }
    if ((tid & 63) == 0) atomicMax(&sm, mykey);
    __syncthreads();
    if (tid == 0) partialmax[blockIdx.x] = sm;
}

// partialmax[1024], entry i belongs to head i&7
__global__ __launch_bounds__(256) void reduce_max2_kernel(
    const unsigned* __restrict__ partialmax, float* __restrict__ headmax)
{
    int tid = threadIdx.x;
    int h = tid >> 5, lane = tid & 31;
    unsigned m = 0u;
#pragma unroll
    for (int k = 0; k < 4; k++) {
        unsigned v = partialmax[(lane + 32 * k) * 8 + h];
        m = (v > m) ? v : m;
    }
    for (int off = 16; off > 0; off >>= 1) {
        unsigned o = __shfl_down(m, off, 32);
        m = (o > m) ? o : m;
    }
    if (lane == 0) headmax[h] = key_to_float(m);
}

// ---------- aggregate7: head-pinned, LDS-staged src + inline exp, psum partials ----------
// block = 32 nodes x 1 head; contiguous CSR range tiled through LDS.
__global__ __launch_bounds__(256) void aggregate7_kernel(
    const unsigned short* __restrict__ vh, const float* __restrict__ scores,
    const int* __restrict__ src_s, const int* __restrict__ offs,
    const float* __restrict__ headmax, unsigned short* __restrict__ aggb,
    float* __restrict__ psum_part)
{
    __shared__ int sSrc[512];
    __shared__ float sP[512];
    __shared__ float blocksum;
    int tid = threadIdx.x;
    int h = blockIdx.x & 7;
    int chunk = blockIdx.x >> 3;
    int nodebase = chunk * 32;
    int g = tid >> 3;            // 0..31: node within chunk
    int ln = tid & 7;            // 4-dim slot
    int node = nodebase + g;
    float m = headmax[h];
    const float* sc_h = scores + (size_t)h * NUM_EDGES;
    const unsigned short* vhh = vh + (size_t)h * NUM_NODES * 32;
    if (tid == 0) blocksum = 0.f;

    int blkstart = offs[nodebase];
    int blkend = offs[(nodebase + 32 < NUM_NODES) ? (nodebase + 32) : NUM_NODES];
    int start = 0, end = 0;
    if (node < NUM_NODES) { start = offs[node]; end = offs[node + 1]; }

    f32x4 a0 = (f32x4)(0.f), a1 = (f32x4)(0.f);
    float ps = 0.f;

    for (int t0 = blkstart; t0 < blkend; t0 += 512) {
        int cnt = min(512, blkend - t0);
        __syncthreads();
        for (int i = tid; i < cnt; i += 256) {
            sSrc[i] = src_s[t0 + i];
            float p = __expf(sc_h[t0 + i] - m);
            sP[i] = p;
            ps += p;
        }
        __syncthreads();
        int lo = (start > t0) ? start : t0;
        int hi = (end < t0 + cnt) ? end : (t0 + cnt);
        int cb = lo;
        for (; cb + 2 <= hi; cb += 2) {
            int i0 = cb - t0;
            int s0 = sSrc[i0], s1 = sSrc[i0 + 1];
            float p0 = sP[i0], p1 = sP[i0 + 1];
            ushort4 v0 = *(const ushort4*)(vhh + (size_t)s0 * 32 + ln * 4);
            ushort4 v1 = *(const ushort4*)(vhh + (size_t)s1 * 32 + ln * 4);
            a0[0] += p0 * bf2f(v0.x); a0[1] += p0 * bf2f(v0.y);
            a0[2] += p0 * bf2f(v0.z); a0[3] += p0 * bf2f(v0.w);
            a1[0] += p1 * bf2f(v1.x); a1[1] += p1 * bf2f(v1.y);
            a1[2] += p1 * bf2f(v1.z); a1[3] += p1 * bf2f(v1.w);
        }
        if (cb < hi) {
            int i0 = cb - t0;
            int s0 = sSrc[i0];
            float p0 = sP[i0];
            ushort4 v0 = *(const ushort4*)(vhh + (size_t)s0 * 32 + ln * 4);
            a0[0] += p0 * bf2f(v0.x); a0[1] += p0 * bf2f(v0.y);
            a0[2] += p0 * bf2f(v0.z); a0[3] += p0 * bf2f(v0.w);
        }
    }

    if (node < NUM_NODES) {
        ushort4 o;
        o.x = f2bf(a0[0] + a1[0]); o.y = f2bf(a0[1] + a1[1]);
        o.z = f2bf(a0[2] + a1[2]); o.w = f2bf(a0[3] + a1[3]);
        *(ushort4*)(aggb + ((size_t)h * NUM_NODES + node) * 32 + ln * 4) = o;
    }

    // block-wide psum (each staged edge counted once)
    __syncthreads();
#pragma unroll
    for (int off = 32; off > 0; off >>= 1) ps += __shfl_xor(ps, off, 64);
    if ((tid & 63) == 0) atomicAdd(&blocksum, ps);
    __syncthreads();
    if (tid == 0) psum_part[blockIdx.x] = blocksum;
}

// psum_part[NCHUNK32*8], entry i belongs to head i&7
__global__ __launch_bounds__(256) void reduce_psum2_kernel(
    const float* __restrict__ psum_part, float* __restrict__ headinv)
{
    int tid = threadIdx.x;
    int h = tid >> 5, lane = tid & 31;
    float s = 0.f;
    for (int i = lane; i < NCHUNK32; i += 32) s += psum_part[i * 8 + h];
    for (int off = 16; off > 0; off >>= 1) s += __shfl_down(s, off, 32);
    if (lane == 0) headinv[h] = 1.f / s;
}

extern "C" void kernel_launch(void* const* d_in, const int* in_sizes, int n_in,
                              void* d_out, int out_size, void* d_ws, size_t ws_size,
                              hipStream_t stream) {
    const float* x = (const float*)d_in[0];
    const int* ei = (const int*)d_in[1];
    const int* src_idx = ei;
    const int* dst_idx = ei + NUM_EDGES;
    const float* edge_time = (const float*)d_in[2];
    const float* node_time = (const float*)d_in[3];
    const float* Wq = (const float*)d_in[4];  const float* bq = (const float*)d_in[5];
    const float* Wk = (const float*)d_in[6];  const float* bk = (const float*)d_in[7];
    const float* Wv = (const float*)d_in[8];  const float* bv = (const float*)d_in[9];
    const float* Wt = (const float*)d_in[10]; const float* bt = (const float*)d_in[11];
    const float* Wo = (const float*)d_in[12]; const float* bo = (const float*)d_in[13];
    float* out = (float*)d_out;

    char* w = (char*)d_ws;
    unsigned short* qb = (unsigned short*)w; w += (size_t)NUM_NODES * 256 * 2;  // [8][N][32]
    unsigned short* kb = (unsigned short*)w; w += (size_t)NUM_NODES * 256 * 2;  // [8][N][32]
    unsigned short* vb = (unsigned short*)w; w += (size_t)NUM_NODES * 256 * 2;  // [8][N][32]
    float* scores = (float*)w;      w += (size_t)NUM_EDGES * 8 * 4;             // [8][E]
    unsigned short* aggb = (unsigned short*)w; w += (size_t)NUM_NODES * 256 * 2; // [8][N][32]
    int* src_s = (int*)w;           w += (size_t)NUM_EDGES * 4;
    int* dst_s = (int*)w;           w += (size_t)NUM_EDGES * 4;
    float* et_s = (float*)w;        w += (size_t)NUM_EDGES * 4;
    int* deg = (int*)w;             w += (size_t)NUM_NODES * 4;
    int* offs = (int*)w;            w += (size_t)(NUM_NODES + 1) * 4;
    int* cursor = (int*)w;          w += (size_t)NUM_NODES * 4;
    unsigned* partialmax = (unsigned*)w; w += 1024 * 4;
    float* psum_part = (float*)w;   w += (size_t)NCHUNK32 * 8 * 4;
    float* headmax = (float*)w;     w += 8 * 4;
    float* headinv = (float*)w;     w += 8 * 4;
    int* blocksum = (int*)w;        w += 64 * 4;
    int* bcarry = (int*)w;          w += 64 * 4;
    unsigned short* Wtb = (unsigned short*)w; w += (size_t)1024 * 256 * 2;
    unsigned short* Wpk = (unsigned short*)w; w += (size_t)1024 * 256 * 2;      // fragment-packed

    hipMemsetAsync(deg, 0, (size_t)NUM_NODES * 4, stream);

    // weight transpose + bf16 cvt (q,k,v,o), then fragment-pack
    dim3 gw(16, 4);
    wtrans_kernel<<<gw, 256, 0, stream>>>(Wq, Wk, Wv, Wo, Wtb);
    wpack_kernel<<<128, 256, 0, stream>>>(Wtb, Wpk);

    // CSR by dst (parallel scan)
    deg_kernel<<<(NUM_EDGES + 255) / 256, 256, 0, stream>>>(dst_idx, deg);
    scanA_kernel<<<SCAN_BLOCKS, 1024, 0, stream>>>(deg, offs, blocksum);
    scanB_kernel<<<1, 64, 0, stream>>>(blocksum, bcarry, offs);
    scanC_kernel<<<(NUM_NODES + 255) / 256, 256, 0, stream>>>(offs, bcarry, cursor);
    fill2_kernel<<<(NUM_EDGES + 255) / 256, 256, 0, stream>>>(src_idx, dst_idx, edge_time,
                                                              cursor, src_s, dst_s, et_s);

    // QKV projection -> head-major bf16 q/k/v  (packed-W, A staged once)
    gemm_qkv_mfma6<<<(NUM_NODES + 63) / 64, 256, 0, stream>>>(
        x, NUM_NODES, Wpk, bq, bk, bv, qb, kb, vb);

    // scores (head-pinned to XCDs) + per-head max
    score3_kernel<<<1024, 256, 0, stream>>>(qb, kb, src_s, dst_s, et_s, node_time,
                                            Wt, bt, scores, partialmax);
    reduce_max2_kernel<<<1, 256, 0, stream>>>(partialmax, headmax);

    // aggregate (head-pinned, LDS-staged src+p, inline exp) + psum partials
    aggregate7_kernel<<<NCHUNK32 * 8, 256, 0, stream>>>(
        vb, scores, src_s, offs, headmax, aggb, psum_part);
    reduce_psum2_kernel<<<1, 256, 0, stream>>>(psum_part, headinv);

    // output projection with per-head 1/sum folded into staging (packed-W)
    gemm_out_mfma6<<<(NUM_NODES + 63) / 64, 256, 0, stream>>>(
        aggb, NUM_NODES, Wpk + (size_t)768 * 256, bo, headinv, out);
}